// Round 6
// baseline (855.838 us; speedup 1.0000x reference)
//
#include <hip/hip_runtime.h>
#include <hip/hip_bf16.h>

typedef __hip_bfloat16 bf16;
typedef __attribute__((ext_vector_type(8))) short short8;
typedef __attribute__((ext_vector_type(4))) short s16x4;
typedef __attribute__((ext_vector_type(4))) float f32x4;

#define B_   4
#define N_   16384
#define D_   192
#define H6   6
#define DH   32
#define MCL  64
#define KC   256
#define DFF  768
#define GW   128
#define MTOK (B_ * N_)    // 65536 tokens

__device__ __forceinline__ bf16 f2b(float x) { return __float2bfloat16(x); }
__device__ __forceinline__ short f2bbits(float x) {
    bf16 h = __float2bfloat16(x); return *(short*)&h;
}

// A-fragment global layout for an MxK bf16 matrix (MFMA 16x16x32 A-operand order):
//   block = (row>>4)*(K>>5) + (k>>5), 512 shorts per block
//   offset = (((k>>3)&3)*16 + (row&15))*8 + (k&7)
// Consumer wave (16 rows) reads af[kt] = block[lane*8 .. +7], one 16B load.

// ---- fallback: zero output (signals ws_size too small via absmax==max|ref|~5.69) ----
__global__ void zero_out_kernel(float* __restrict__ out, size_t n) {
    size_t i = blockIdx.x * (size_t)blockDim.x + threadIdx.x;
    if (i < n) out[i] = 0.f;
}

// ---- order: scanline keys are a bijection onto 0..n-1 -> direct scatter ----
__global__ void build_idx(const float* __restrict__ pos, int* __restrict__ order) {
    int tid = blockIdx.x * blockDim.x + threadIdx.x;
    if (tid >= B_ * N_) return;
    int b = tid / N_;
    int ix = (int)floorf(pos[(size_t)tid * 2 + 0]);
    int iy = (int)floorf(pos[(size_t)tid * 2 + 1]);
    int key = iy * GW + ((iy & 1) ? (GW - 1 - ix) : ix);
    key = (int)(((unsigned)key) & (N_ - 1));
    order[(size_t)b * N_ + key] = tid % N_;
}

// ---- all-weights prep: fp32 row-major [K][N] -> bf16 MFMA-B-fragment order ----
__global__ void wprep_all(const float* __restrict__ wq, const float* __restrict__ wp,
                          const float* __restrict__ wf1, const float* __restrict__ wf2,
                          bf16* __restrict__ out) {
    int tid = blockIdx.x * blockDim.x + threadIdx.x;
    if (tid >= 2 * 442368) return;
    int l = tid / 442368, r = tid % 442368;
    const float* src; bf16* dst; int K, Nn, e;
    if (r < 110592)      { src = wq  + (size_t)l * 110592; dst = out + (size_t)l * 442368;          K = 192; Nn = 576; e = r; }
    else if (r < 147456) { src = wp  + (size_t)l * 36864;  dst = out + (size_t)l * 442368 + 110592; K = 192; Nn = 192; e = r - 110592; }
    else if (r < 294912) { src = wf1 + (size_t)l * 147456; dst = out + (size_t)l * 442368 + 147456; K = 192; Nn = 768; e = r - 147456; }
    else                 { src = wf2 + (size_t)l * 147456; dst = out + (size_t)l * 442368 + 294912; K = 768; Nn = 192; e = r - 294912; }
    int k = e / Nn, n = e % Nn;
    int idx = ((n >> 4) * (K >> 5) + (k >> 5)) * 512 + (((k >> 3) & 3) * 16 + (n & 15)) * 8 + (k & 7);
    dst[idx] = f2b(src[e]);
}

// ---- Kernel A: fused-LN GEMM, K=192, A-stationary (BM=64, grid = M/64) ----
// Swapped MFMA in both paths (lane holds row=l16, 4 consecutive cols).
// FRAGOUT=false: row-major s16x4 (8B) stores (qkv).
// FRAGOUT=true : 8B stores into A-fragment-order buffer for downstream GEMM (fc1).
template<bool GELU, bool FRAGOUT>
__global__ __launch_bounds__(256, 4) void gemm_lnk192(
    const float* __restrict__ Ain, const float* __restrict__ lng, const float* __restrict__ lnb,
    const bf16* __restrict__ Wf, const float* __restrict__ bias,
    bf16* __restrict__ Cout, int Nn) {
    __shared__ short Asl[4 * 6 * 512];   // 24.6 KB A fragments
    int tid = threadIdx.x;
    int bm = blockIdx.x;
    int w = tid >> 6, lane = tid & 63;
    {
        int r = tid >> 2, qq = tid & 3;           // 4 threads per row, 48 floats each
        const float* xr = Ain + ((size_t)(bm * 64) + r) * 192 + qq * 48;
        float4 va[12];
        float s = 0.f, ss = 0.f;
        #pragma unroll
        for (int j = 0; j < 12; j++) {
            va[j] = ((const float4*)xr)[j];
            s  += va[j].x + va[j].y + va[j].z + va[j].w;
            ss += va[j].x * va[j].x + va[j].y * va[j].y + va[j].z * va[j].z + va[j].w * va[j].w;
        }
        s  += __shfl_xor(s, 1);  s  += __shfl_xor(s, 2);
        ss += __shfl_xor(ss, 1); ss += __shfl_xor(ss, 2);
        float mean = s * (1.f / 192.f);
        float var  = ss * (1.f / 192.f) - mean * mean;
        float rs   = rsqrtf(var + 1e-5f);
        const float4* gg = (const float4*)(lng + qq * 48);
        const float4* bb = (const float4*)(lnb + qq * 48);
        #pragma unroll
        for (int j = 0; j < 6; j++) {
            float4 g0 = gg[2 * j], g1 = gg[2 * j + 1], b0 = bb[2 * j], b1 = bb[2 * j + 1];
            float4 x0 = va[2 * j], x1 = va[2 * j + 1];
            short8 o;
            o[0] = f2bbits((x0.x - mean) * rs * g0.x + b0.x);
            o[1] = f2bbits((x0.y - mean) * rs * g0.y + b0.y);
            o[2] = f2bbits((x0.z - mean) * rs * g0.z + b0.z);
            o[3] = f2bbits((x0.w - mean) * rs * g0.w + b0.w);
            o[4] = f2bbits((x1.x - mean) * rs * g1.x + b1.x);
            o[5] = f2bbits((x1.y - mean) * rs * g1.y + b1.y);
            o[6] = f2bbits((x1.z - mean) * rs * g1.z + b1.z);
            o[7] = f2bbits((x1.w - mean) * rs * g1.w + b1.w);
            int k0 = qq * 48 + j * 8;
            int kt = k0 >> 5, qd = (k0 >> 3) & 3;
            *(short8*)&Asl[((r >> 4) * 6 + kt) * 512 + (qd * 16 + (r & 15)) * 8] = o;
        }
    }
    __syncthreads();
    short8 af[6];
    #pragma unroll
    for (int kt = 0; kt < 6; kt++)
        af[kt] = *(short8*)&Asl[(w * 6 + kt) * 512 + lane * 8];
    int quad = lane >> 4, l16 = lane & 15;
    int ntiles = Nn >> 4;
    for (int nt = 0; nt < ntiles; nt++) {
        const short* bp = (const short*)Wf + ((size_t)nt * 6) * 512 + lane * 8;
        f32x4 acc = {};
        #pragma unroll
        for (int kt = 0; kt < 6; kt++) {
            short8 b = *(const short8*)(bp + kt * 512);
            acc = __builtin_amdgcn_mfma_f32_16x16x32_bf16(b, af[kt], acc, 0, 0, 0);  // swapped -> C^T
        }
        // lane holds output row = l16 (token), cols nt*16 + quad*4 .. +3
        int colb = nt * 16 + quad * 4;
        float4 bv = *(const float4*)(bias + colb);
        float v[4] = { acc[0] + bv.x, acc[1] + bv.y, acc[2] + bv.z, acc[3] + bv.w };
        if (GELU) {
            #pragma unroll
            for (int rr = 0; rr < 4; rr++) {
                float u = v[rr];
                float inner = 0.7978845608028654f * (u + 0.044715f * u * u * u);
                inner = fminf(fmaxf(inner, -12.f), 12.f);
                float e = __expf(2.f * inner);
                v[rr] = 0.5f * u * (1.f + (e - 1.f) / (e + 1.f));
            }
        }
        s16x4 o;
        o[0] = f2bbits(v[0]); o[1] = f2bbits(v[1]); o[2] = f2bbits(v[2]); o[3] = f2bbits(v[3]);
        if (!FRAGOUT) {
            *(s16x4*)((short*)Cout + ((size_t)(bm * 64) + w * 16 + l16) * Nn + colb) = o;
        } else {
            // frag dest: block = mt*(Nn>>5) + (nt>>1); qd = (nt&1)*2 + (quad>>1); k&7 = (quad&1)*4+rr
            size_t dst = ((size_t)(bm * 4 + w) * (Nn >> 5) + (nt >> 1)) * 512
                       + (((nt & 1) * 2 + (quad >> 1)) * 16 + l16) * 8 + (quad & 1) * 4;
            *(s16x4*)((short*)Cout + dst) = o;
        }
    }
}

// ---- Kernel B: N=192 GEMM + residual, A fragment-direct, MT=2 (BM=128) ----
// Each wave owns TWO 16-row m-tiles: B-fragment stream amortized over 32 rows.
__global__ __launch_bounds__(256) void gemm_n192(
    const bf16* __restrict__ Af, const bf16* __restrict__ Wf, const float* __restrict__ bias,
    const float* __restrict__ Rsrc, float* __restrict__ Rdst, int K) {
    int tid = threadIdx.x;
    int bm = blockIdx.x;
    int w = tid >> 6, lane = tid & 63;
    int quad = lane >> 4, l16 = lane & 15;
    int nkc = K / 192, ktn = K >> 5;
    int mt0 = bm * 8 + w * 2;
    f32x4 acc[2][12] = {};
    for (int kc = 0; kc < nkc; kc++) {
        short8 af[2][6];
        #pragma unroll
        for (int i = 0; i < 2; i++) {
            const short* ap = (const short*)Af + ((size_t)(mt0 + i) * ktn + kc * 6) * 512 + lane * 8;
            #pragma unroll
            for (int kt = 0; kt < 6; kt++)
                af[i][kt] = *(const short8*)(ap + kt * 512);
        }
        #pragma unroll
        for (int nt = 0; nt < 12; nt++) {
            const short* bp = (const short*)Wf + ((size_t)nt * ktn + kc * 6) * 512 + lane * 8;
            #pragma unroll
            for (int kt = 0; kt < 6; kt++) {
                short8 b = *(const short8*)(bp + kt * 512);
                acc[0][nt] = __builtin_amdgcn_mfma_f32_16x16x32_bf16(af[0][kt], b, acc[0][nt], 0, 0, 0);
                acc[1][nt] = __builtin_amdgcn_mfma_f32_16x16x32_bf16(af[1][kt], b, acc[1][nt], 0, 0, 0);
            }
        }
    }
    #pragma unroll
    for (int i = 0; i < 2; i++) {
        int row0 = (mt0 + i) * 16 + quad * 4;
        #pragma unroll
        for (int nt = 0; nt < 12; nt++) {
            int col = nt * 16 + l16;
            float bv = bias[col];
            #pragma unroll
            for (int rr = 0; rr < 4; rr++) {
                size_t idx = (size_t)(row0 + rr) * 192 + col;
                Rdst[idx] = acc[i][nt][rr] + bv + Rsrc[idx];
            }
        }
    }
}

// ---- MFMA cluster attention: one wave per (head, cluster, batch) ----
// Output written in A-fragment order for the proj GEMM (head h == k-tile h).
#define PST 72   // P LDS row stride (shorts), 16B-aligned rows
#define VST 72   // vT LDS row stride
#define OST 40   // O  LDS row stride
__global__ __launch_bounds__(64) void attn_mfma(const bf16* __restrict__ qkv,
                                                const int* __restrict__ order,
                                                bf16* __restrict__ outb) {
    __shared__ short vT[32 * VST];   // [d][p]
    __shared__ short Pl[64 * PST];   // [qrow][p]; reused as O [qrow][d] stride OST
    const float scale = 0.17677669529663687f;  // 32^-0.5
    int h = blockIdx.x, c = blockIdx.y, b = blockIdx.z;
    int lane = threadIdx.x;
    int l16 = lane & 15, quad = lane >> 4;
    int t = (int)(((unsigned)order[(size_t)b * N_ + c * MCL + lane]) & (N_ - 1));
    const short* qb = (const short*)qkv + (size_t)b * N_ * 576;
    // stage V transposed: lane p writes column p of vT
    {
        const short* vp = qb + (size_t)t * 576 + 384 + h * 32;
        short8 v[4];
        #pragma unroll
        for (int i = 0; i < 4; i++) v[i] = *(const short8*)(vp + i * 8);
        #pragma unroll
        for (int i = 0; i < 4; i++)
            #pragma unroll
            for (int e = 0; e < 8; e++)
                vT[(i * 8 + e) * VST + lane] = v[i][e];
    }
    // Q A-frags / K B-frags: global gather of rows tile*16+l16, dims quad*8..+7
    short8 aq[4], bk[4];
    #pragma unroll
    for (int i = 0; i < 4; i++) {
        int tr = __shfl(t, i * 16 + l16);
        const short* rp = qb + (size_t)tr * 576 + h * 32 + quad * 8;
        aq[i] = *(const short8*)rp;
        bk[i] = *(const short8*)(rp + 192);
    }
    // S = Q K^T (16 mfma)
    f32x4 S[4][4];
    #pragma unroll
    for (int mt = 0; mt < 4; mt++)
        #pragma unroll
        for (int nt = 0; nt < 4; nt++) {
            f32x4 z = {};
            S[mt][nt] = __builtin_amdgcn_mfma_f32_16x16x32_bf16(aq[mt], bk[nt], z, 0, 0, 0);
        }
    __syncthreads();   // vT staging visible
    // softmax rows (no max-pass: |S*scale| tiny; clamp for safety), P normalized -> LDS
    #pragma unroll
    for (int mt = 0; mt < 4; mt++)
        #pragma unroll
        for (int r = 0; r < 4; r++) {
            float e0, e1, e2, e3, s;
            float v0 = S[mt][0][r] * scale, v1 = S[mt][1][r] * scale;
            float v2 = S[mt][2][r] * scale, v3 = S[mt][3][r] * scale;
            e0 = __expf(fminf(fmaxf(v0, -30.f), 30.f));
            e1 = __expf(fminf(fmaxf(v1, -30.f), 30.f));
            e2 = __expf(fminf(fmaxf(v2, -30.f), 30.f));
            e3 = __expf(fminf(fmaxf(v3, -30.f), 30.f));
            s = e0 + e1 + e2 + e3;
            s += __shfl_xor(s, 1); s += __shfl_xor(s, 2);
            s += __shfl_xor(s, 4); s += __shfl_xor(s, 8);
            float inv = 1.f / s;
            int row = mt * 16 + quad * 4 + r;
            Pl[row * PST +  0 + l16] = f2bbits(e0 * inv);
            Pl[row * PST + 16 + l16] = f2bbits(e1 * inv);
            Pl[row * PST + 32 + l16] = f2bbits(e2 * inv);
            Pl[row * PST + 48 + l16] = f2bbits(e3 * inv);
        }
    __syncthreads();
    // O = P V (16 mfma)
    short8 ap[4][2], bv[2][2];
    #pragma unroll
    for (int mt = 0; mt < 4; mt++)
        #pragma unroll
        for (int kt = 0; kt < 2; kt++)
            ap[mt][kt] = *(const short8*)&Pl[(mt * 16 + l16) * PST + kt * 32 + quad * 8];
    #pragma unroll
    for (int nt = 0; nt < 2; nt++)
        #pragma unroll
        for (int kt = 0; kt < 2; kt++)
            bv[nt][kt] = *(const short8*)&vT[(nt * 16 + l16) * VST + kt * 32 + quad * 8];
    f32x4 O[4][2] = {};
    #pragma unroll
    for (int mt = 0; mt < 4; mt++)
        #pragma unroll
        for (int nt = 0; nt < 2; nt++)
            #pragma unroll
            for (int kt = 0; kt < 2; kt++)
                O[mt][nt] = __builtin_amdgcn_mfma_f32_16x16x32_bf16(ap[mt][kt], bv[nt][kt], O[mt][nt], 0, 0, 0);
    __syncthreads();   // P reads complete before overwrite with O
    short* Ol = Pl;
    #pragma unroll
    for (int mt = 0; mt < 4; mt++) {
        int row = mt * 16 + quad * 4;
        #pragma unroll
        for (int nt = 0; nt < 2; nt++)
            #pragma unroll
            for (int rr = 0; rr < 4; rr++)
                Ol[(row + rr) * OST + nt * 16 + l16] = f2bbits(O[mt][nt][rr]);
    }
    __syncthreads();
    // lane writes its token's 32 dims into A-fragment order:
    // block = (b*1024 + (t>>4))*6 + h ; per j: 16B at (j*16 + (t&15))*8
    {
        size_t blk = ((size_t)b * (N_ >> 4) + (t >> 4)) * 6 + h;
        short* op = (short*)outb + blk * 512 + (size_t)(t & 15) * 8;
        #pragma unroll
        for (int j = 0; j < 4; j++)
            *(short8*)(op + j * 128) = *(const short8*)&Ol[lane * OST + j * 8];
    }
}

extern "C" void kernel_launch(void* const* d_in, const int* in_sizes, int n_in,
                              void* d_out, int out_size, void* d_ws, size_t ws_size,
                              hipStream_t stream) {
    const float* x_in   = (const float*)d_in[0];
    const float* pos    = (const float*)d_in[1];
    const float* ln1_g  = (const float*)d_in[2];
    const float* ln1_b  = (const float*)d_in[3];
    const float* w_qkv  = (const float*)d_in[4];
    const float* b_qkv  = (const float*)d_in[5];
    const float* w_proj = (const float*)d_in[6];
    const float* b_proj = (const float*)d_in[7];
    const float* ln2_g  = (const float*)d_in[8];
    const float* ln2_b  = (const float*)d_in[9];
    const float* w_fc1  = (const float*)d_in[10];
    const float* b_fc1  = (const float*)d_in[11];
    const float* w_fc2  = (const float*)d_in[12];
    const float* b_fc2  = (const float*)d_in[13];

    size_t sz_x     = (size_t)MTOK * D_ * 4;        // 50.3 MB fp32 residual
    size_t sz_xnob  = (size_t)MTOK * D_ * 2;        // 25.2 MB attn out bf16 (frag order)
    size_t sz_cbuf  = (size_t)MTOK * DFF * 2;       // 100.7 MB qkv(576 rowmajor)/hidden(768 frag)
    size_t sz_order = (size_t)B_ * N_ * 4;          //  0.26 MB
    size_t sz_wbuf  = (size_t)2 * 442368 * 2;       //  1.73 MB frag-order weights
    size_t need = sz_x + sz_xnob + sz_cbuf + sz_order + sz_wbuf;
    if (ws_size < need) {
        zero_out_kernel<<<(out_size + 255) / 256, 256, 0, stream>>>((float*)d_out, (size_t)out_size);
        return;
    }
    char* ws = (char*)d_ws;
    float* x_f32 = (float*)ws;  ws += sz_x;
    bf16*  xnob  = (bf16*)ws;   ws += sz_xnob;
    bf16*  cbuf  = (bf16*)ws;   ws += sz_cbuf;
    int*   order = (int*)ws;    ws += sz_order;
    bf16*  wbuf  = (bf16*)ws;   ws += sz_wbuf;

    bf16* wq[2]; bf16* wp[2]; bf16* wf1[2]; bf16* wf2[2];
    for (int l = 0; l < 2; ++l) {
        bf16* p = wbuf + (size_t)l * 442368;
        wq[l]  = p;
        wp[l]  = p + 110592;
        wf1[l] = p + 147456;
        wf2[l] = p + 294912;
    }
    wprep_all<<<(2 * 442368 + 255) / 256, 256, 0, stream>>>(w_qkv, w_proj, w_fc1, w_fc2, wbuf);
    build_idx<<<(B_ * N_ + 255) / 256, 256, 0, stream>>>(pos, order);

    for (int l = 0; l < 2; ++l) {
        const float* xsrc = (l == 0) ? x_in : x_f32;
        float* rdst_proj  = x_f32;
        float* rdst_fc2   = (l == 1) ? (float*)d_out : x_f32;
        gemm_lnk192<false, false><<<MTOK / 64, 256, 0, stream>>>(
            xsrc, ln1_g + l * D_, ln1_b + l * D_, wq[l], b_qkv + l * 576, cbuf, 576);
        attn_mfma<<<dim3(H6, KC, B_), 64, 0, stream>>>(cbuf, order, xnob);
        gemm_n192<<<MTOK / 128, 256, 0, stream>>>(
            xnob, wp[l], b_proj + l * 192, xsrc, rdst_proj, 192);
        gemm_lnk192<true, true><<<MTOK / 64, 256, 0, stream>>>(
            x_f32, ln2_g + l * D_, ln2_b + l * D_, wf1[l], b_fc1 + l * 768, cbuf, 768);
        gemm_n192<<<MTOK / 128, 256, 0, stream>>>(
            cbuf, wf2[l], b_fc2 + l * 192, x_f32, rdst_fc2, 768);
    }
}

// Round 7
// 717.054 us; speedup vs baseline: 1.1935x; 1.1935x over previous
//
#include <hip/hip_runtime.h>
#include <hip/hip_bf16.h>

typedef __hip_bfloat16 bf16;
typedef __attribute__((ext_vector_type(8))) short short8;
typedef __attribute__((ext_vector_type(4))) short s16x4;
typedef __attribute__((ext_vector_type(4))) float f32x4;

#define B_   4
#define N_   16384
#define D_   192
#define H6   6
#define DH   32
#define MCL  64
#define KC   256
#define DFF  768
#define GW   128
#define MTOK (B_ * N_)    // 65536 tokens

__device__ __forceinline__ bf16 f2b(float x) { return __float2bfloat16(x); }
__device__ __forceinline__ short f2bbits(float x) {
    bf16 h = __float2bfloat16(x); return *(short*)&h;
}

// ---- fallback: zero output (signals ws_size too small via absmax==max|ref|~5.69) ----
__global__ void zero_out_kernel(float* __restrict__ out, size_t n) {
    size_t i = blockIdx.x * (size_t)blockDim.x + threadIdx.x;
    if (i < n) out[i] = 0.f;
}

// ---- order: scanline keys are a bijection onto 0..n-1 -> direct scatter ----
__global__ void build_idx(const float* __restrict__ pos, int* __restrict__ order) {
    int tid = blockIdx.x * blockDim.x + threadIdx.x;
    if (tid >= B_ * N_) return;
    int b = tid / N_;
    int ix = (int)floorf(pos[(size_t)tid * 2 + 0]);
    int iy = (int)floorf(pos[(size_t)tid * 2 + 1]);
    int key = iy * GW + ((iy & 1) ? (GW - 1 - ix) : ix);
    key = (int)(((unsigned)key) & (N_ - 1));
    order[(size_t)b * N_ + key] = tid % N_;
}

// ---- all-weights prep: fp32 row-major [K][N] -> bf16 MFMA-B-fragment order ----
__global__ void wprep_all(const float* __restrict__ wq, const float* __restrict__ wp,
                          const float* __restrict__ wf1, const float* __restrict__ wf2,
                          bf16* __restrict__ out) {
    int tid = blockIdx.x * blockDim.x + threadIdx.x;
    if (tid >= 2 * 442368) return;
    int l = tid / 442368, r = tid % 442368;
    const float* src; bf16* dst; int K, Nn, e;
    if (r < 110592)      { src = wq  + (size_t)l * 110592; dst = out + (size_t)l * 442368;          K = 192; Nn = 576; e = r; }
    else if (r < 147456) { src = wp  + (size_t)l * 36864;  dst = out + (size_t)l * 442368 + 110592; K = 192; Nn = 192; e = r - 110592; }
    else if (r < 294912) { src = wf1 + (size_t)l * 147456; dst = out + (size_t)l * 442368 + 147456; K = 192; Nn = 768; e = r - 147456; }
    else                 { src = wf2 + (size_t)l * 147456; dst = out + (size_t)l * 442368 + 294912; K = 768; Nn = 192; e = r - 294912; }
    int k = e / Nn, n = e % Nn;
    int idx = ((n >> 4) * (K >> 5) + (k >> 5)) * 512 + (((k >> 3) & 3) * 16 + (n & 15)) * 8 + (k & 7);
    dst[idx] = f2b(src[e]);
}

// ---- Kernel A: fused-LN GEMM, K=192, A-stationary (BM=64, grid = M/64) ----
// Swapped MFMA (computes C^T): lane holds row=l16, cols quad*4..+3
// -> epilogue is one s16x4 (8B) row-major store per n-tile.  [R4-measured]
template<bool GELU>
__global__ __launch_bounds__(256) void gemm_lnk192(
    const float* __restrict__ Ain, const float* __restrict__ lng, const float* __restrict__ lnb,
    const bf16* __restrict__ Wf, const float* __restrict__ bias,
    bf16* __restrict__ Cout, int Nn) {
    __shared__ short Asl[4 * 6 * 512];   // 24.6 KB A fragments
    int tid = threadIdx.x;
    int bm = blockIdx.x;
    int w = tid >> 6, lane = tid & 63;
    {
        int r = tid >> 2, qq = tid & 3;           // 4 threads per row, 48 floats each
        const float* xr = Ain + ((size_t)(bm * 64) + r) * 192 + qq * 48;
        float4 va[12];
        float s = 0.f, ss = 0.f;
        #pragma unroll
        for (int j = 0; j < 12; j++) {
            va[j] = ((const float4*)xr)[j];
            s  += va[j].x + va[j].y + va[j].z + va[j].w;
            ss += va[j].x * va[j].x + va[j].y * va[j].y + va[j].z * va[j].z + va[j].w * va[j].w;
        }
        s  += __shfl_xor(s, 1);  s  += __shfl_xor(s, 2);
        ss += __shfl_xor(ss, 1); ss += __shfl_xor(ss, 2);
        float mean = s * (1.f / 192.f);
        float var  = ss * (1.f / 192.f) - mean * mean;
        float rs   = rsqrtf(var + 1e-5f);
        const float4* gg = (const float4*)(lng + qq * 48);
        const float4* bb = (const float4*)(lnb + qq * 48);
        #pragma unroll
        for (int j = 0; j < 6; j++) {
            float4 g0 = gg[2 * j], g1 = gg[2 * j + 1], b0 = bb[2 * j], b1 = bb[2 * j + 1];
            float4 x0 = va[2 * j], x1 = va[2 * j + 1];
            short8 o;
            o[0] = f2bbits((x0.x - mean) * rs * g0.x + b0.x);
            o[1] = f2bbits((x0.y - mean) * rs * g0.y + b0.y);
            o[2] = f2bbits((x0.z - mean) * rs * g0.z + b0.z);
            o[3] = f2bbits((x0.w - mean) * rs * g0.w + b0.w);
            o[4] = f2bbits((x1.x - mean) * rs * g1.x + b1.x);
            o[5] = f2bbits((x1.y - mean) * rs * g1.y + b1.y);
            o[6] = f2bbits((x1.z - mean) * rs * g1.z + b1.z);
            o[7] = f2bbits((x1.w - mean) * rs * g1.w + b1.w);
            int k0 = qq * 48 + j * 8;
            int kt = k0 >> 5, qd = (k0 >> 3) & 3;
            *(short8*)&Asl[((r >> 4) * 6 + kt) * 512 + (qd * 16 + (r & 15)) * 8] = o;
        }
    }
    __syncthreads();
    short8 af[6];
    #pragma unroll
    for (int kt = 0; kt < 6; kt++)
        af[kt] = *(short8*)&Asl[(w * 6 + kt) * 512 + lane * 8];
    int quad = lane >> 4, l16 = lane & 15;
    int ntiles = Nn >> 4;
    size_t rowbase = ((size_t)(bm * 64) + w * 16 + l16) * Nn;
    for (int nt = 0; nt < ntiles; nt++) {
        const short* bp = (const short*)Wf + ((size_t)nt * 6) * 512 + lane * 8;
        f32x4 acc = {};
        #pragma unroll
        for (int kt = 0; kt < 6; kt++) {
            short8 b = *(const short8*)(bp + kt * 512);
            acc = __builtin_amdgcn_mfma_f32_16x16x32_bf16(b, af[kt], acc, 0, 0, 0);  // swapped -> C^T
        }
        int col = nt * 16 + quad * 4;
        float4 bv = *(const float4*)(bias + col);
        float v[4] = { acc[0] + bv.x, acc[1] + bv.y, acc[2] + bv.z, acc[3] + bv.w };
        if (GELU) {
            #pragma unroll
            for (int rr = 0; rr < 4; rr++) {
                float u = v[rr];
                float inner = 0.7978845608028654f * (u + 0.044715f * u * u * u);
                inner = fminf(fmaxf(inner, -12.f), 12.f);
                float e = __expf(2.f * inner);
                v[rr] = 0.5f * u * (1.f + (e - 1.f) / (e + 1.f));
            }
        }
        s16x4 o;
        o[0] = f2bbits(v[0]); o[1] = f2bbits(v[1]); o[2] = f2bbits(v[2]); o[3] = f2bbits(v[3]);
        *(s16x4*)((short*)Cout + rowbase + col) = o;
    }
}

// ---- Kernel B: N=192 full-width GEMM + residual (R0 baseline, grid = M/128) ----
__global__ __launch_bounds__(256) void gemm_n192(
    const bf16* __restrict__ A, const bf16* __restrict__ Wf, const float* __restrict__ bias,
    const float* __restrict__ Rsrc, float* __restrict__ Rdst, int K) {
    __shared__ short Asl[8 * 6 * 512];
    int tid = threadIdx.x;
    int bm = blockIdx.x;
    int w = tid >> 6, lane = tid & 63;
    int quad = lane >> 4, l16 = lane & 15;
    int nkc = K / 192, ktn = K >> 5;
    int r = tid >> 1, half = tid & 1;
    f32x4 acc[12][2] = {};
    for (int kc = 0; kc < nkc; kc++) {
        if (kc) __syncthreads();
        const short* ar = (const short*)A + ((size_t)(bm * 128) + r) * K + kc * 192 + half * 96;
        #pragma unroll
        for (int j = 0; j < 12; j++) {
            short8 v = *(const short8*)(ar + j * 8);
            int k0 = half * 96 + j * 8;
            int kt = k0 >> 5, qd = (k0 >> 3) & 3;
            *(short8*)&Asl[((r >> 4) * 6 + kt) * 512 + (qd * 16 + (r & 15)) * 8] = v;
        }
        __syncthreads();
        short8 af[2][6];
        #pragma unroll
        for (int mt = 0; mt < 2; mt++)
            #pragma unroll
            for (int kt = 0; kt < 6; kt++)
                af[mt][kt] = *(short8*)&Asl[((w * 2 + mt) * 6 + kt) * 512 + lane * 8];
        #pragma unroll
        for (int nt = 0; nt < 12; nt++) {
            const short* bp = (const short*)Wf + ((size_t)nt * ktn + kc * 6) * 512 + lane * 8;
            #pragma unroll
            for (int kt = 0; kt < 6; kt++) {
                short8 b = *(const short8*)(bp + kt * 512);
                acc[nt][0] = __builtin_amdgcn_mfma_f32_16x16x32_bf16(af[0][kt], b, acc[nt][0], 0, 0, 0);
                acc[nt][1] = __builtin_amdgcn_mfma_f32_16x16x32_bf16(af[1][kt], b, acc[nt][1], 0, 0, 0);
            }
        }
    }
    #pragma unroll
    for (int nt = 0; nt < 12; nt++) {
        int col = nt * 16 + l16;
        float bv = bias[col];
        #pragma unroll
        for (int mt = 0; mt < 2; mt++) {
            int row0 = bm * 128 + (w * 2 + mt) * 16 + quad * 4;
            #pragma unroll
            for (int rr = 0; rr < 4; rr++) {
                size_t idx = (size_t)(row0 + rr) * 192 + col;
                Rdst[idx] = acc[nt][mt][rr] + bv + Rsrc[idx];
            }
        }
    }
}

// ---- MFMA cluster attention: one wave per (head, cluster, batch) ----
// S = Q.K^T (Q/K frags gathered from global), softmax in C-layout,
// P (normalized, bf16) -> LDS -> A-frags; V staged transposed -> B-frags; O = P.V
#define PST 72   // P LDS row stride (shorts), 16B-aligned rows
#define VST 72   // vT LDS row stride
#define OST 40   // O  LDS row stride
__global__ __launch_bounds__(64) void attn_mfma(const bf16* __restrict__ qkv,
                                                const int* __restrict__ order,
                                                bf16* __restrict__ outb) {
    __shared__ short vT[32 * VST];   // [d][p]
    __shared__ short Pl[64 * PST];   // [qrow][p]; reused as O [qrow][d] stride OST
    const float scale = 0.17677669529663687f;  // 32^-0.5
    int h = blockIdx.x, c = blockIdx.y, b = blockIdx.z;
    int lane = threadIdx.x;
    int l16 = lane & 15, quad = lane >> 4;
    int t = (int)(((unsigned)order[(size_t)b * N_ + c * MCL + lane]) & (N_ - 1));
    const short* qb = (const short*)qkv + (size_t)b * N_ * 576;
    // stage V transposed: lane p writes column p of vT
    {
        const short* vp = qb + (size_t)t * 576 + 384 + h * 32;
        short8 v[4];
        #pragma unroll
        for (int i = 0; i < 4; i++) v[i] = *(const short8*)(vp + i * 8);
        #pragma unroll
        for (int i = 0; i < 4; i++)
            #pragma unroll
            for (int e = 0; e < 8; e++)
                vT[(i * 8 + e) * VST + lane] = v[i][e];
    }
    // Q A-frags / K B-frags: global gather of rows tile*16+l16, dims quad*8..+7
    short8 aq[4], bk[4];
    #pragma unroll
    for (int i = 0; i < 4; i++) {
        int tr = __shfl(t, i * 16 + l16);
        const short* rp = qb + (size_t)tr * 576 + h * 32 + quad * 8;
        aq[i] = *(const short8*)rp;
        bk[i] = *(const short8*)(rp + 192);
    }
    // S = Q K^T (16 mfma)
    f32x4 S[4][4];
    #pragma unroll
    for (int mt = 0; mt < 4; mt++)
        #pragma unroll
        for (int nt = 0; nt < 4; nt++) {
            f32x4 z = {};
            S[mt][nt] = __builtin_amdgcn_mfma_f32_16x16x32_bf16(aq[mt], bk[nt], z, 0, 0, 0);
        }
    __syncthreads();   // vT staging visible
    // softmax rows (no max-pass: |S*scale| tiny; clamp for safety), P normalized -> LDS
    #pragma unroll
    for (int mt = 0; mt < 4; mt++)
        #pragma unroll
        for (int r = 0; r < 4; r++) {
            float e0, e1, e2, e3, s;
            float v0 = S[mt][0][r] * scale, v1 = S[mt][1][r] * scale;
            float v2 = S[mt][2][r] * scale, v3 = S[mt][3][r] * scale;
            e0 = __expf(fminf(fmaxf(v0, -30.f), 30.f));
            e1 = __expf(fminf(fmaxf(v1, -30.f), 30.f));
            e2 = __expf(fminf(fmaxf(v2, -30.f), 30.f));
            e3 = __expf(fminf(fmaxf(v3, -30.f), 30.f));
            s = e0 + e1 + e2 + e3;
            s += __shfl_xor(s, 1); s += __shfl_xor(s, 2);
            s += __shfl_xor(s, 4); s += __shfl_xor(s, 8);
            float inv = 1.f / s;
            int row = mt * 16 + quad * 4 + r;
            Pl[row * PST +  0 + l16] = f2bbits(e0 * inv);
            Pl[row * PST + 16 + l16] = f2bbits(e1 * inv);
            Pl[row * PST + 32 + l16] = f2bbits(e2 * inv);
            Pl[row * PST + 48 + l16] = f2bbits(e3 * inv);
        }
    __syncthreads();
    // O = P V (16 mfma)
    short8 ap[4][2], bv[2][2];
    #pragma unroll
    for (int mt = 0; mt < 4; mt++)
        #pragma unroll
        for (int kt = 0; kt < 2; kt++)
            ap[mt][kt] = *(const short8*)&Pl[(mt * 16 + l16) * PST + kt * 32 + quad * 8];
    #pragma unroll
    for (int nt = 0; nt < 2; nt++)
        #pragma unroll
        for (int kt = 0; kt < 2; kt++)
            bv[nt][kt] = *(const short8*)&vT[(nt * 16 + l16) * VST + kt * 32 + quad * 8];
    f32x4 O[4][2] = {};
    #pragma unroll
    for (int mt = 0; mt < 4; mt++)
        #pragma unroll
        for (int nt = 0; nt < 2; nt++)
            #pragma unroll
            for (int kt = 0; kt < 2; kt++)
                O[mt][nt] = __builtin_amdgcn_mfma_f32_16x16x32_bf16(ap[mt][kt], bv[nt][kt], O[mt][nt], 0, 0, 0);
    __syncthreads();   // P reads complete before overwrite with O
    short* Ol = Pl;
    #pragma unroll
    for (int mt = 0; mt < 4; mt++) {
        int row = mt * 16 + quad * 4;
        #pragma unroll
        for (int nt = 0; nt < 2; nt++)
            #pragma unroll
            for (int rr = 0; rr < 4; rr++)
                Ol[(row + rr) * OST + nt * 16 + l16] = f2bbits(O[mt][nt][rr]);
    }
    __syncthreads();
    // lane gathers its own token's 32 dims, one 64B contiguous global write
    short* op = (short*)outb + ((size_t)b * N_ + t) * 192 + h * 32;
    #pragma unroll
    for (int j = 0; j < 4; j++)
        *(short8*)(op + j * 8) = *(const short8*)&Ol[lane * OST + j * 8];
}

extern "C" void kernel_launch(void* const* d_in, const int* in_sizes, int n_in,
                              void* d_out, int out_size, void* d_ws, size_t ws_size,
                              hipStream_t stream) {
    const float* x_in   = (const float*)d_in[0];
    const float* pos    = (const float*)d_in[1];
    const float* ln1_g  = (const float*)d_in[2];
    const float* ln1_b  = (const float*)d_in[3];
    const float* w_qkv  = (const float*)d_in[4];
    const float* b_qkv  = (const float*)d_in[5];
    const float* w_proj = (const float*)d_in[6];
    const float* b_proj = (const float*)d_in[7];
    const float* ln2_g  = (const float*)d_in[8];
    const float* ln2_b  = (const float*)d_in[9];
    const float* w_fc1  = (const float*)d_in[10];
    const float* b_fc1  = (const float*)d_in[11];
    const float* w_fc2  = (const float*)d_in[12];
    const float* b_fc2  = (const float*)d_in[13];

    size_t sz_x     = (size_t)MTOK * D_ * 4;        // 50.3 MB fp32 residual
    size_t sz_xnob  = (size_t)MTOK * D_ * 2;        // 25.2 MB attn out bf16
    size_t sz_cbuf  = (size_t)MTOK * DFF * 2;       // 100.7 MB qkv(576)/hidden(768)
    size_t sz_order = (size_t)B_ * N_ * 4;          //  0.26 MB
    size_t sz_wbuf  = (size_t)2 * 442368 * 2;       //  1.73 MB frag-order weights
    size_t need = sz_x + sz_xnob + sz_cbuf + sz_order + sz_wbuf;
    if (ws_size < need) {
        zero_out_kernel<<<(out_size + 255) / 256, 256, 0, stream>>>((float*)d_out, (size_t)out_size);
        return;
    }
    char* ws = (char*)d_ws;
    float* x_f32 = (float*)ws;  ws += sz_x;
    bf16*  xnob  = (bf16*)ws;   ws += sz_xnob;
    bf16*  cbuf  = (bf16*)ws;   ws += sz_cbuf;
    int*   order = (int*)ws;    ws += sz_order;
    bf16*  wbuf  = (bf16*)ws;   ws += sz_wbuf;

    bf16* wq[2]; bf16* wp[2]; bf16* wf1[2]; bf16* wf2[2];
    for (int l = 0; l < 2; ++l) {
        bf16* p = wbuf + (size_t)l * 442368;
        wq[l]  = p;
        wp[l]  = p + 110592;
        wf1[l] = p + 147456;
        wf2[l] = p + 294912;
    }
    wprep_all<<<(2 * 442368 + 255) / 256, 256, 0, stream>>>(w_qkv, w_proj, w_fc1, w_fc2, wbuf);
    build_idx<<<(B_ * N_ + 255) / 256, 256, 0, stream>>>(pos, order);

    for (int l = 0; l < 2; ++l) {
        const float* xsrc = (l == 0) ? x_in : x_f32;
        float* rdst_proj  = x_f32;
        float* rdst_fc2   = (l == 1) ? (float*)d_out : x_f32;
        gemm_lnk192<false><<<MTOK / 64, 256, 0, stream>>>(
            xsrc, ln1_g + l * D_, ln1_b + l * D_, wq[l], b_qkv + l * 576, cbuf, 576);
        attn_mfma<<<dim3(H6, KC, B_), 64, 0, stream>>>(cbuf, order, xnob);
        gemm_n192<<<MTOK / 128, 256, 0, stream>>>(
            xnob, wp[l], b_proj + l * 192, xsrc, rdst_proj, 192);
        gemm_lnk192<true><<<MTOK / 64, 256, 0, stream>>>(
            x_f32, ln2_g + l * D_, ln2_b + l * D_, wf1[l], b_fc1 + l * 768, cbuf, 768);
        gemm_n192<<<MTOK / 128, 256, 0, stream>>>(
            cbuf, wf2[l], b_fc2 + l * 192, x_f32, rdst_fc2, 768);
    }
}

// Round 8
// 532.365 us; speedup vs baseline: 1.6076x; 1.3469x over previous
//
#include <hip/hip_runtime.h>
#include <hip/hip_bf16.h>

typedef __hip_bfloat16 bf16;
typedef __attribute__((ext_vector_type(8))) short short8;
typedef __attribute__((ext_vector_type(4))) short s16x4;
typedef __attribute__((ext_vector_type(4))) float f32x4;

#define B_   4
#define N_   16384
#define D_   192
#define H6   6
#define DH   32
#define MCL  64
#define KC   256
#define DFF  768
#define GW   128
#define MTOK (B_ * N_)    // 65536 tokens

__device__ __forceinline__ bf16 f2b(float x) { return __float2bfloat16(x); }
__device__ __forceinline__ short f2bbits(float x) {
    bf16 h = __float2bfloat16(x); return *(short*)&h;
}

// ---- fallback: zero output (signals ws_size too small via absmax==max|ref|~5.69) ----
__global__ void zero_out_kernel(float* __restrict__ out, size_t n) {
    size_t i = blockIdx.x * (size_t)blockDim.x + threadIdx.x;
    if (i < n) out[i] = 0.f;
}

// ---- order: scanline keys are a bijection onto 0..n-1 -> direct scatter ----
__global__ void build_idx(const float* __restrict__ pos, int* __restrict__ order) {
    int tid = blockIdx.x * blockDim.x + threadIdx.x;
    if (tid >= B_ * N_) return;
    int b = tid / N_;
    int ix = (int)floorf(pos[(size_t)tid * 2 + 0]);
    int iy = (int)floorf(pos[(size_t)tid * 2 + 1]);
    int key = iy * GW + ((iy & 1) ? (GW - 1 - ix) : ix);
    key = (int)(((unsigned)key) & (N_ - 1));
    order[(size_t)b * N_ + key] = tid % N_;
}

// ---- all-weights prep: fp32 row-major [K][N] -> bf16 MFMA-B-fragment order ----
__global__ void wprep_all(const float* __restrict__ wq, const float* __restrict__ wp,
                          const float* __restrict__ wf1, const float* __restrict__ wf2,
                          bf16* __restrict__ out) {
    int tid = blockIdx.x * blockDim.x + threadIdx.x;
    if (tid >= 2 * 442368) return;
    int l = tid / 442368, r = tid % 442368;
    const float* src; bf16* dst; int K, Nn, e;
    if (r < 110592)      { src = wq  + (size_t)l * 110592; dst = out + (size_t)l * 442368;          K = 192; Nn = 576; e = r; }
    else if (r < 147456) { src = wp  + (size_t)l * 36864;  dst = out + (size_t)l * 442368 + 110592; K = 192; Nn = 192; e = r - 110592; }
    else if (r < 294912) { src = wf1 + (size_t)l * 147456; dst = out + (size_t)l * 442368 + 147456; K = 192; Nn = 768; e = r - 147456; }
    else                 { src = wf2 + (size_t)l * 147456; dst = out + (size_t)l * 442368 + 294912; K = 768; Nn = 192; e = r - 294912; }
    int k = e / Nn, n = e % Nn;
    int idx = ((n >> 4) * (K >> 5) + (k >> 5)) * 512 + (((k >> 3) & 3) * 16 + (n & 15)) * 8 + (k & 7);
    dst[idx] = f2b(src[e]);
}

// ---- Kernel A: fused-LN GEMM, K=192 (qkv), BM=64 — R1-measured version ----
template<bool GELU>
__global__ __launch_bounds__(256, 4) void gemm_lnk192(
    const float* __restrict__ Ain, const float* __restrict__ lng, const float* __restrict__ lnb,
    const bf16* __restrict__ Wf, const float* __restrict__ bias,
    bf16* __restrict__ Cout, int Nn) {
    __shared__ short Asl[4 * 6 * 512];   // 24.6 KB
    int tid = threadIdx.x;
    int bm = blockIdx.x;
    int w = tid >> 6, lane = tid & 63;
    {
        int r = tid >> 2, qq = tid & 3;           // 4 threads per row, 48 floats each
        const float* xr = Ain + ((size_t)(bm * 64) + r) * 192 + qq * 48;
        float4 va[12];
        float s = 0.f, ss = 0.f;
        #pragma unroll
        for (int j = 0; j < 12; j++) {
            va[j] = ((const float4*)xr)[j];
            s  += va[j].x + va[j].y + va[j].z + va[j].w;
            ss += va[j].x * va[j].x + va[j].y * va[j].y + va[j].z * va[j].z + va[j].w * va[j].w;
        }
        s  += __shfl_xor(s, 1);  s  += __shfl_xor(s, 2);
        ss += __shfl_xor(ss, 1); ss += __shfl_xor(ss, 2);
        float mean = s * (1.f / 192.f);
        float var  = ss * (1.f / 192.f) - mean * mean;
        float rs   = rsqrtf(var + 1e-5f);
        const float4* gg = (const float4*)(lng + qq * 48);
        const float4* bb = (const float4*)(lnb + qq * 48);
        #pragma unroll
        for (int j = 0; j < 6; j++) {
            float4 g0 = gg[2 * j], g1 = gg[2 * j + 1], b0 = bb[2 * j], b1 = bb[2 * j + 1];
            float4 x0 = va[2 * j], x1 = va[2 * j + 1];
            short8 o;
            o[0] = f2bbits((x0.x - mean) * rs * g0.x + b0.x);
            o[1] = f2bbits((x0.y - mean) * rs * g0.y + b0.y);
            o[2] = f2bbits((x0.z - mean) * rs * g0.z + b0.z);
            o[3] = f2bbits((x0.w - mean) * rs * g0.w + b0.w);
            o[4] = f2bbits((x1.x - mean) * rs * g1.x + b1.x);
            o[5] = f2bbits((x1.y - mean) * rs * g1.y + b1.y);
            o[6] = f2bbits((x1.z - mean) * rs * g1.z + b1.z);
            o[7] = f2bbits((x1.w - mean) * rs * g1.w + b1.w);
            int k0 = qq * 48 + j * 8;
            int kt = k0 >> 5, qd = (k0 >> 3) & 3;
            *(short8*)&Asl[((r >> 4) * 6 + kt) * 512 + (qd * 16 + (r & 15)) * 8] = o;
        }
    }
    __syncthreads();
    short8 af[6];
    #pragma unroll
    for (int kt = 0; kt < 6; kt++)
        af[kt] = *(short8*)&Asl[(w * 6 + kt) * 512 + lane * 8];
    int quad = lane >> 4, l16 = lane & 15;
    int ntiles = Nn >> 4;
    for (int nt = 0; nt < ntiles; nt++) {
        const short* bp = (const short*)Wf + ((size_t)nt * 6) * 512 + lane * 8;
        f32x4 acc = {};
        #pragma unroll
        for (int kt = 0; kt < 6; kt++) {
            short8 b = *(const short8*)(bp + kt * 512);
            acc = __builtin_amdgcn_mfma_f32_16x16x32_bf16(af[kt], b, acc, 0, 0, 0);
        }
        int col = nt * 16 + l16;
        float bv = bias[col];
        int row0 = bm * 64 + w * 16 + quad * 4;
        #pragma unroll
        for (int rr = 0; rr < 4; rr++) {
            float v = acc[rr] + bv;
            if (GELU) {
                float inner = 0.7978845608028654f * (v + 0.044715f * v * v * v);
                inner = fminf(fmaxf(inner, -12.f), 12.f);
                float e = __expf(2.f * inner);
                v = 0.5f * v * (1.f + (e - 1.f) / (e + 1.f));
            }
            Cout[(size_t)(row0 + rr) * Nn + col] = f2b(v);
        }
    }
}

// ---- Kernel B: N=192 GEMM + residual (R0-measured version, BM=128) ----
__global__ __launch_bounds__(256) void gemm_n192(
    const bf16* __restrict__ A, const bf16* __restrict__ Wf, const float* __restrict__ bias,
    const float* __restrict__ Rsrc, float* __restrict__ Rdst, int K) {
    __shared__ short Asl[8 * 6 * 512];
    int tid = threadIdx.x;
    int bm = blockIdx.x;
    int w = tid >> 6, lane = tid & 63;
    int quad = lane >> 4, l16 = lane & 15;
    int nkc = K / 192, ktn = K >> 5;
    int r = tid >> 1, half = tid & 1;
    f32x4 acc[12][2] = {};
    for (int kc = 0; kc < nkc; kc++) {
        if (kc) __syncthreads();
        const short* ar = (const short*)A + ((size_t)(bm * 128) + r) * K + kc * 192 + half * 96;
        #pragma unroll
        for (int j = 0; j < 12; j++) {
            short8 v = *(const short8*)(ar + j * 8);
            int k0 = half * 96 + j * 8;
            int kt = k0 >> 5, qd = (k0 >> 3) & 3;
            *(short8*)&Asl[((r >> 4) * 6 + kt) * 512 + (qd * 16 + (r & 15)) * 8] = v;
        }
        __syncthreads();
        short8 af[2][6];
        #pragma unroll
        for (int mt = 0; mt < 2; mt++)
            #pragma unroll
            for (int kt = 0; kt < 6; kt++)
                af[mt][kt] = *(short8*)&Asl[((w * 2 + mt) * 6 + kt) * 512 + lane * 8];
        #pragma unroll
        for (int nt = 0; nt < 12; nt++) {
            const short* bp = (const short*)Wf + ((size_t)nt * ktn + kc * 6) * 512 + lane * 8;
            #pragma unroll
            for (int kt = 0; kt < 6; kt++) {
                short8 b = *(const short8*)(bp + kt * 512);
                acc[nt][0] = __builtin_amdgcn_mfma_f32_16x16x32_bf16(af[0][kt], b, acc[nt][0], 0, 0, 0);
                acc[nt][1] = __builtin_amdgcn_mfma_f32_16x16x32_bf16(af[1][kt], b, acc[nt][1], 0, 0, 0);
            }
        }
    }
    #pragma unroll
    for (int nt = 0; nt < 12; nt++) {
        int col = nt * 16 + l16;
        float bv = bias[col];
        #pragma unroll
        for (int mt = 0; mt < 2; mt++) {
            int row0 = bm * 128 + (w * 2 + mt) * 16 + quad * 4;
            #pragma unroll
            for (int rr = 0; rr < 4; rr++) {
                size_t idx = (size_t)(row0 + rr) * 192 + col;
                Rdst[idx] = acc[nt][mt][rr] + bv + Rsrc[idx];
            }
        }
    }
}

// ---- Kernel C: fused MLP — x += gelu(LN(x)@W1+b1)@W2+b2, BM=64 ----
// Hidden never touches HBM: computed 192 cols at a time (quarter), staged in
// LDS in A-fragment order (swapped-MFMA C^T writes s16x4 directly in frag
// layout, proven in R5's FRAGOUT path), consumed by fc2 with accumulation.
__global__ __launch_bounds__(256) void mlp_fused(
    const float* __restrict__ Ain, const float* __restrict__ lng, const float* __restrict__ lnb,
    const bf16* __restrict__ W1f, const float* __restrict__ b1,
    const bf16* __restrict__ W2f, const float* __restrict__ b2,
    const float* __restrict__ Rsrc, float* __restrict__ Rdst) {
    __shared__ short Asl[4 * 6 * 512];   // 24.6 KB  LN(x) A-frags (4 m-tiles x 6 k-tiles)
    __shared__ short Hsl[4 * 6 * 512];   // 24.6 KB  hidden quarter A-frags (4 m x 6 k)
    int tid = threadIdx.x;
    int bm = blockIdx.x;
    int w = tid >> 6, lane = tid & 63;
    int quad = lane >> 4, l16 = lane & 15;
    // stage LN(x) A-frags (identical to gemm_lnk192 staging)
    {
        int r = tid >> 2, qq = tid & 3;
        const float* xr = Ain + ((size_t)(bm * 64) + r) * 192 + qq * 48;
        float4 va[12];
        float s = 0.f, ss = 0.f;
        #pragma unroll
        for (int j = 0; j < 12; j++) {
            va[j] = ((const float4*)xr)[j];
            s  += va[j].x + va[j].y + va[j].z + va[j].w;
            ss += va[j].x * va[j].x + va[j].y * va[j].y + va[j].z * va[j].z + va[j].w * va[j].w;
        }
        s  += __shfl_xor(s, 1);  s  += __shfl_xor(s, 2);
        ss += __shfl_xor(ss, 1); ss += __shfl_xor(ss, 2);
        float mean = s * (1.f / 192.f);
        float var  = ss * (1.f / 192.f) - mean * mean;
        float rs   = rsqrtf(var + 1e-5f);
        const float4* gg = (const float4*)(lng + qq * 48);
        const float4* bb = (const float4*)(lnb + qq * 48);
        #pragma unroll
        for (int j = 0; j < 6; j++) {
            float4 g0 = gg[2 * j], g1 = gg[2 * j + 1], b0 = bb[2 * j], b1v = bb[2 * j + 1];
            float4 x0 = va[2 * j], x1 = va[2 * j + 1];
            short8 o;
            o[0] = f2bbits((x0.x - mean) * rs * g0.x + b0.x);
            o[1] = f2bbits((x0.y - mean) * rs * g0.y + b0.y);
            o[2] = f2bbits((x0.z - mean) * rs * g0.z + b0.z);
            o[3] = f2bbits((x0.w - mean) * rs * g0.w + b0.w);
            o[4] = f2bbits((x1.x - mean) * rs * g1.x + b1v.x);
            o[5] = f2bbits((x1.y - mean) * rs * g1.y + b1v.y);
            o[6] = f2bbits((x1.z - mean) * rs * g1.z + b1v.z);
            o[7] = f2bbits((x1.w - mean) * rs * g1.w + b1v.w);
            int k0 = qq * 48 + j * 8;
            int kt = k0 >> 5, qd = (k0 >> 3) & 3;
            *(short8*)&Asl[((r >> 4) * 6 + kt) * 512 + (qd * 16 + (r & 15)) * 8] = o;
        }
    }
    __syncthreads();
    f32x4 acc2[3][4] = {};   // fc2 accum: [own n-tile j][m-tile]
    for (int qtr = 0; qtr < 4; qtr++) {
        if (qtr) __syncthreads();       // prior fc2 reads of Hsl complete
        // ---- fc1 quarter: wave w computes n-tiles (qtr*12 + w*3 .. +2), all 4 m-tiles ----
        short8 af[4][6];
        #pragma unroll
        for (int mt = 0; mt < 4; mt++)
            #pragma unroll
            for (int kt = 0; kt < 6; kt++)
                af[mt][kt] = *(short8*)&Asl[(mt * 6 + kt) * 512 + lane * 8];
        #pragma unroll
        for (int j = 0; j < 3; j++) {
            int nth = w * 3 + j;                        // n-tile within quarter (0..11)
            int ntg = qtr * 12 + nth;                   // global hidden n-tile (0..47)
            const short* bp = (const short*)W1f + ((size_t)ntg * 6) * 512 + lane * 8;
            short8 bfr[6];
            #pragma unroll
            for (int kt = 0; kt < 6; kt++) bfr[kt] = *(const short8*)(bp + kt * 512);
            #pragma unroll
            for (int mt = 0; mt < 4; mt++) {
                f32x4 a = {};
                #pragma unroll
                for (int kt = 0; kt < 6; kt++)
                    a = __builtin_amdgcn_mfma_f32_16x16x32_bf16(bfr[kt], af[mt][kt], a, 0, 0, 0);  // C^T
                // lane holds token row = l16 (of m-tile mt), hidden cols ntg*16+quad*4..+3
                int colb = ntg * 16 + quad * 4;
                s16x4 o;
                #pragma unroll
                for (int rr = 0; rr < 4; rr++) {
                    float u = a[rr] + b1[colb + rr];
                    float inner = 0.7978845608028654f * (u + 0.044715f * u * u * u);
                    inner = fminf(fmaxf(inner, -12.f), 12.f);
                    float e = __expf(2.f * inner);
                    o[rr] = f2bbits(0.5f * u * (1.f + (e - 1.f) / (e + 1.f)));
                }
                // A-frag store (R5-proven formula): kk = nth*16+quad*4+rr within quarter
                *(s16x4*)&Hsl[(mt * 6 + (nth >> 1)) * 512
                              + (((nth & 1) * 2 + (quad >> 1)) * 16 + l16) * 8 + (quad & 1) * 4] = o;
            }
        }
        __syncthreads();
        // ---- fc2 partial: wave w owns output n-tiles w*3..w*3+2, K = this quarter ----
        #pragma unroll
        for (int kt = 0; kt < 6; kt++) {
            short8 afh[4];
            #pragma unroll
            for (int mt = 0; mt < 4; mt++)
                afh[mt] = *(short8*)&Hsl[(mt * 6 + kt) * 512 + lane * 8];
            #pragma unroll
            for (int j = 0; j < 3; j++) {
                int nt = w * 3 + j;
                const short* bp = (const short*)W2f + ((size_t)nt * 24 + qtr * 6 + kt) * 512 + lane * 8;
                short8 b = *(const short8*)bp;
                #pragma unroll
                for (int mt = 0; mt < 4; mt++)
                    acc2[j][mt] = __builtin_amdgcn_mfma_f32_16x16x32_bf16(afh[mt], b, acc2[j][mt], 0, 0, 0);
            }
        }
    }
    // ---- epilogue: bias + residual, scalar stores (R0-proven pattern) ----
    #pragma unroll
    for (int j = 0; j < 3; j++) {
        int col = (w * 3 + j) * 16 + l16;
        float bv = b2[col];
        #pragma unroll
        for (int mt = 0; mt < 4; mt++) {
            int row0 = bm * 64 + mt * 16 + quad * 4;
            #pragma unroll
            for (int rr = 0; rr < 4; rr++) {
                size_t idx = (size_t)(row0 + rr) * 192 + col;
                Rdst[idx] = acc2[j][mt][rr] + bv + Rsrc[idx];
            }
        }
    }
}

// ---- MFMA cluster attention: one wave per (head, cluster, batch) ----
#define PST 72   // P LDS row stride (shorts), 16B-aligned rows
#define VST 72   // vT LDS row stride
#define OST 40   // O  LDS row stride
__global__ __launch_bounds__(64) void attn_mfma(const bf16* __restrict__ qkv,
                                                const int* __restrict__ order,
                                                bf16* __restrict__ outb) {
    __shared__ short vT[32 * VST];   // [d][p]
    __shared__ short Pl[64 * PST];   // [qrow][p]; reused as O [qrow][d] stride OST
    const float scale = 0.17677669529663687f;  // 32^-0.5
    int h = blockIdx.x, c = blockIdx.y, b = blockIdx.z;
    int lane = threadIdx.x;
    int l16 = lane & 15, quad = lane >> 4;
    int t = (int)(((unsigned)order[(size_t)b * N_ + c * MCL + lane]) & (N_ - 1));
    const short* qb = (const short*)qkv + (size_t)b * N_ * 576;
    {
        const short* vp = qb + (size_t)t * 576 + 384 + h * 32;
        short8 v[4];
        #pragma unroll
        for (int i = 0; i < 4; i++) v[i] = *(const short8*)(vp + i * 8);
        #pragma unroll
        for (int i = 0; i < 4; i++)
            #pragma unroll
            for (int e = 0; e < 8; e++)
                vT[(i * 8 + e) * VST + lane] = v[i][e];
    }
    short8 aq[4], bk[4];
    #pragma unroll
    for (int i = 0; i < 4; i++) {
        int tr = __shfl(t, i * 16 + l16);
        const short* rp = qb + (size_t)tr * 576 + h * 32 + quad * 8;
        aq[i] = *(const short8*)rp;
        bk[i] = *(const short8*)(rp + 192);
    }
    f32x4 S[4][4];
    #pragma unroll
    for (int mt = 0; mt < 4; mt++)
        #pragma unroll
        for (int nt = 0; nt < 4; nt++) {
            f32x4 z = {};
            S[mt][nt] = __builtin_amdgcn_mfma_f32_16x16x32_bf16(aq[mt], bk[nt], z, 0, 0, 0);
        }
    __syncthreads();
    #pragma unroll
    for (int mt = 0; mt < 4; mt++)
        #pragma unroll
        for (int r = 0; r < 4; r++) {
            float e0, e1, e2, e3, s;
            float v0 = S[mt][0][r] * scale, v1 = S[mt][1][r] * scale;
            float v2 = S[mt][2][r] * scale, v3 = S[mt][3][r] * scale;
            e0 = __expf(fminf(fmaxf(v0, -30.f), 30.f));
            e1 = __expf(fminf(fmaxf(v1, -30.f), 30.f));
            e2 = __expf(fminf(fmaxf(v2, -30.f), 30.f));
            e3 = __expf(fminf(fmaxf(v3, -30.f), 30.f));
            s = e0 + e1 + e2 + e3;
            s += __shfl_xor(s, 1); s += __shfl_xor(s, 2);
            s += __shfl_xor(s, 4); s += __shfl_xor(s, 8);
            float inv = 1.f / s;
            int row = mt * 16 + quad * 4 + r;
            Pl[row * PST +  0 + l16] = f2bbits(e0 * inv);
            Pl[row * PST + 16 + l16] = f2bbits(e1 * inv);
            Pl[row * PST + 32 + l16] = f2bbits(e2 * inv);
            Pl[row * PST + 48 + l16] = f2bbits(e3 * inv);
        }
    __syncthreads();
    short8 ap[4][2], bv[2][2];
    #pragma unroll
    for (int mt = 0; mt < 4; mt++)
        #pragma unroll
        for (int kt = 0; kt < 2; kt++)
            ap[mt][kt] = *(const short8*)&Pl[(mt * 16 + l16) * PST + kt * 32 + quad * 8];
    #pragma unroll
    for (int nt = 0; nt < 2; nt++)
        #pragma unroll
        for (int kt = 0; kt < 2; kt++)
            bv[nt][kt] = *(const short8*)&vT[(nt * 16 + l16) * VST + kt * 32 + quad * 8];
    f32x4 O[4][2] = {};
    #pragma unroll
    for (int mt = 0; mt < 4; mt++)
        #pragma unroll
        for (int nt = 0; nt < 2; nt++)
            #pragma unroll
            for (int kt = 0; kt < 2; kt++)
                O[mt][nt] = __builtin_amdgcn_mfma_f32_16x16x32_bf16(ap[mt][kt], bv[nt][kt], O[mt][nt], 0, 0, 0);
    __syncthreads();
    short* Ol = Pl;
    #pragma unroll
    for (int mt = 0; mt < 4; mt++) {
        int row = mt * 16 + quad * 4;
        #pragma unroll
        for (int nt = 0; nt < 2; nt++)
            #pragma unroll
            for (int rr = 0; rr < 4; rr++)
                Ol[(row + rr) * OST + nt * 16 + l16] = f2bbits(O[mt][nt][rr]);
    }
    __syncthreads();
    short* op = (short*)outb + ((size_t)b * N_ + t) * 192 + h * 32;
    #pragma unroll
    for (int j = 0; j < 4; j++)
        *(short8*)(op + j * 8) = *(const short8*)&Ol[lane * OST + j * 8];
}

extern "C" void kernel_launch(void* const* d_in, const int* in_sizes, int n_in,
                              void* d_out, int out_size, void* d_ws, size_t ws_size,
                              hipStream_t stream) {
    const float* x_in   = (const float*)d_in[0];
    const float* pos    = (const float*)d_in[1];
    const float* ln1_g  = (const float*)d_in[2];
    const float* ln1_b  = (const float*)d_in[3];
    const float* w_qkv  = (const float*)d_in[4];
    const float* b_qkv  = (const float*)d_in[5];
    const float* w_proj = (const float*)d_in[6];
    const float* b_proj = (const float*)d_in[7];
    const float* ln2_g  = (const float*)d_in[8];
    const float* ln2_b  = (const float*)d_in[9];
    const float* w_fc1  = (const float*)d_in[10];
    const float* b_fc1  = (const float*)d_in[11];
    const float* w_fc2  = (const float*)d_in[12];
    const float* b_fc2  = (const float*)d_in[13];

    size_t sz_x     = (size_t)MTOK * D_ * 4;        // 50.3 MB fp32 residual
    size_t sz_xnob  = (size_t)MTOK * D_ * 2;        // 25.2 MB attn out bf16
    size_t sz_cbuf  = (size_t)MTOK * DFF * 2;       // 100.7 MB qkv buffer
    size_t sz_order = (size_t)B_ * N_ * 4;          //  0.26 MB
    size_t sz_wbuf  = (size_t)2 * 442368 * 2;       //  1.73 MB frag-order weights
    size_t need = sz_x + sz_xnob + sz_cbuf + sz_order + sz_wbuf;
    if (ws_size < need) {
        zero_out_kernel<<<(out_size + 255) / 256, 256, 0, stream>>>((float*)d_out, (size_t)out_size);
        return;
    }
    char* ws = (char*)d_ws;
    float* x_f32 = (float*)ws;  ws += sz_x;
    bf16*  xnob  = (bf16*)ws;   ws += sz_xnob;
    bf16*  cbuf  = (bf16*)ws;   ws += sz_cbuf;
    int*   order = (int*)ws;    ws += sz_order;
    bf16*  wbuf  = (bf16*)ws;   ws += sz_wbuf;

    bf16* wq[2]; bf16* wp[2]; bf16* wf1[2]; bf16* wf2[2];
    for (int l = 0; l < 2; ++l) {
        bf16* p = wbuf + (size_t)l * 442368;
        wq[l]  = p;
        wp[l]  = p + 110592;
        wf1[l] = p + 147456;
        wf2[l] = p + 294912;
    }
    wprep_all<<<(2 * 442368 + 255) / 256, 256, 0, stream>>>(w_qkv, w_proj, w_fc1, w_fc2, wbuf);
    build_idx<<<(B_ * N_ + 255) / 256, 256, 0, stream>>>(pos, order);

    for (int l = 0; l < 2; ++l) {
        const float* xsrc = (l == 0) ? x_in : x_f32;
        float* rdst_mlp = (l == 1) ? (float*)d_out : x_f32;
        gemm_lnk192<false><<<MTOK / 64, 256, 0, stream>>>(
            xsrc, ln1_g + l * D_, ln1_b + l * D_, wq[l], b_qkv + l * 576, cbuf, 576);
        attn_mfma<<<dim3(H6, KC, B_), 64, 0, stream>>>(cbuf, order, xnob);
        gemm_n192<<<MTOK / 128, 256, 0, stream>>>(
            xnob, wp[l], b_proj + l * 192, xsrc, x_f32, 192);
        mlp_fused<<<MTOK / 64, 256, 0, stream>>>(
            x_f32, ln2_g + l * D_, ln2_b + l * D_,
            wf1[l], b_fc1 + l * 768, wf2[l], b_fc2 + l * 192,
            x_f32, rdst_mlp);
    }
}

// Round 9
// 510.518 us; speedup vs baseline: 1.6764x; 1.0428x over previous
//
#include <hip/hip_runtime.h>
#include <hip/hip_bf16.h>

typedef __hip_bfloat16 bf16;
typedef __attribute__((ext_vector_type(8))) short short8;
typedef __attribute__((ext_vector_type(4))) short s16x4;
typedef __attribute__((ext_vector_type(4))) float f32x4;

#define B_   4
#define N_   16384
#define D_   192
#define H6   6
#define DH   32
#define MCL  64
#define KC   256
#define DFF  768
#define GW   128
#define MTOK (B_ * N_)    // 65536 tokens
#define XST  196          // Xl fp32 row stride (16B-aligned, 196%32=4 banks spread)

__device__ __forceinline__ bf16 f2b(float x) { return __float2bfloat16(x); }
__device__ __forceinline__ short f2bbits(float x) {
    bf16 h = __float2bfloat16(x); return *(short*)&h;
}

// ---- fallback: zero output (signals ws_size too small via absmax==max|ref|~5.69) ----
__global__ void zero_out_kernel(float* __restrict__ out, size_t n) {
    size_t i = blockIdx.x * (size_t)blockDim.x + threadIdx.x;
    if (i < n) out[i] = 0.f;
}

// ---- order: scanline keys are a bijection onto 0..n-1 -> direct scatter ----
__global__ void build_idx(const float* __restrict__ pos, int* __restrict__ order) {
    int tid = blockIdx.x * blockDim.x + threadIdx.x;
    if (tid >= B_ * N_) return;
    int b = tid / N_;
    int ix = (int)floorf(pos[(size_t)tid * 2 + 0]);
    int iy = (int)floorf(pos[(size_t)tid * 2 + 1]);
    int key = iy * GW + ((iy & 1) ? (GW - 1 - ix) : ix);
    key = (int)(((unsigned)key) & (N_ - 1));
    order[(size_t)b * N_ + key] = tid % N_;
}

// ---- all-weights prep: fp32 row-major [K][N] -> bf16 MFMA-B-fragment order ----
__global__ void wprep_all(const float* __restrict__ wq, const float* __restrict__ wp,
                          const float* __restrict__ wf1, const float* __restrict__ wf2,
                          bf16* __restrict__ out) {
    int tid = blockIdx.x * blockDim.x + threadIdx.x;
    if (tid >= 2 * 442368) return;
    int l = tid / 442368, r = tid % 442368;
    const float* src; bf16* dst; int K, Nn, e;
    if (r < 110592)      { src = wq  + (size_t)l * 110592; dst = out + (size_t)l * 442368;          K = 192; Nn = 576; e = r; }
    else if (r < 147456) { src = wp  + (size_t)l * 36864;  dst = out + (size_t)l * 442368 + 110592; K = 192; Nn = 192; e = r - 110592; }
    else if (r < 294912) { src = wf1 + (size_t)l * 147456; dst = out + (size_t)l * 442368 + 147456; K = 192; Nn = 768; e = r - 147456; }
    else                 { src = wf2 + (size_t)l * 147456; dst = out + (size_t)l * 442368 + 294912; K = 768; Nn = 192; e = r - 294912; }
    int k = e / Nn, n = e % Nn;
    int idx = ((n >> 4) * (K >> 5) + (k >> 5)) * 512 + (((k >> 3) & 3) * 16 + (n & 15)) * 8 + (k & 7);
    dst[idx] = f2b(src[e]);
}

// ---- Kernel A: fused-LN GEMM, K=192 (qkv), BM=64 — R1-measured version ----
template<bool GELU>
__global__ __launch_bounds__(256, 4) void gemm_lnk192(
    const float* __restrict__ Ain, const float* __restrict__ lng, const float* __restrict__ lnb,
    const bf16* __restrict__ Wf, const float* __restrict__ bias,
    bf16* __restrict__ Cout, int Nn) {
    __shared__ short Asl[4 * 6 * 512];   // 24.6 KB
    int tid = threadIdx.x;
    int bm = blockIdx.x;
    int w = tid >> 6, lane = tid & 63;
    {
        int r = tid >> 2, qq = tid & 3;           // 4 threads per row, 48 floats each
        const float* xr = Ain + ((size_t)(bm * 64) + r) * 192 + qq * 48;
        float4 va[12];
        float s = 0.f, ss = 0.f;
        #pragma unroll
        for (int j = 0; j < 12; j++) {
            va[j] = ((const float4*)xr)[j];
            s  += va[j].x + va[j].y + va[j].z + va[j].w;
            ss += va[j].x * va[j].x + va[j].y * va[j].y + va[j].z * va[j].z + va[j].w * va[j].w;
        }
        s  += __shfl_xor(s, 1);  s  += __shfl_xor(s, 2);
        ss += __shfl_xor(ss, 1); ss += __shfl_xor(ss, 2);
        float mean = s * (1.f / 192.f);
        float var  = ss * (1.f / 192.f) - mean * mean;
        float rs   = rsqrtf(var + 1e-5f);
        const float4* gg = (const float4*)(lng + qq * 48);
        const float4* bb = (const float4*)(lnb + qq * 48);
        #pragma unroll
        for (int j = 0; j < 6; j++) {
            float4 g0 = gg[2 * j], g1 = gg[2 * j + 1], b0 = bb[2 * j], b1 = bb[2 * j + 1];
            float4 x0 = va[2 * j], x1 = va[2 * j + 1];
            short8 o;
            o[0] = f2bbits((x0.x - mean) * rs * g0.x + b0.x);
            o[1] = f2bbits((x0.y - mean) * rs * g0.y + b0.y);
            o[2] = f2bbits((x0.z - mean) * rs * g0.z + b0.z);
            o[3] = f2bbits((x0.w - mean) * rs * g0.w + b0.w);
            o[4] = f2bbits((x1.x - mean) * rs * g1.x + b1.x);
            o[5] = f2bbits((x1.y - mean) * rs * g1.y + b1.y);
            o[6] = f2bbits((x1.z - mean) * rs * g1.z + b1.z);
            o[7] = f2bbits((x1.w - mean) * rs * g1.w + b1.w);
            int k0 = qq * 48 + j * 8;
            int kt = k0 >> 5, qd = (k0 >> 3) & 3;
            *(short8*)&Asl[((r >> 4) * 6 + kt) * 512 + (qd * 16 + (r & 15)) * 8] = o;
        }
    }
    __syncthreads();
    short8 af[6];
    #pragma unroll
    for (int kt = 0; kt < 6; kt++)
        af[kt] = *(short8*)&Asl[(w * 6 + kt) * 512 + lane * 8];
    int quad = lane >> 4, l16 = lane & 15;
    int ntiles = Nn >> 4;
    for (int nt = 0; nt < ntiles; nt++) {
        const short* bp = (const short*)Wf + ((size_t)nt * 6) * 512 + lane * 8;
        f32x4 acc = {};
        #pragma unroll
        for (int kt = 0; kt < 6; kt++) {
            short8 b = *(const short8*)(bp + kt * 512);
            acc = __builtin_amdgcn_mfma_f32_16x16x32_bf16(af[kt], b, acc, 0, 0, 0);
        }
        int col = nt * 16 + l16;
        float bv = bias[col];
        int row0 = bm * 64 + w * 16 + quad * 4;
        #pragma unroll
        for (int rr = 0; rr < 4; rr++) {
            float v = acc[rr] + bv;
            if (GELU) {
                float inner = 0.7978845608028654f * (v + 0.044715f * v * v * v);
                inner = fminf(fmaxf(inner, -12.f), 12.f);
                float e = __expf(2.f * inner);
                v = 0.5f * v * (1.f + (e - 1.f) / (e + 1.f));
            }
            Cout[(size_t)(row0 + rr) * Nn + col] = f2b(v);
        }
    }
}

// ---- Kernel C: fused proj + residual + LN2 + MLP + residual, BM=64 ----
// x1 = xsrc + xnob@Wp+bp lives only in LDS (Xl); hidden lives only in LDS (Bsl).
// Per layer saves the 50MB x1 write + 50MB x1 fetch of the split version.
__global__ __launch_bounds__(256) void pm_fused(
    const bf16* __restrict__ Anob,                       // attn out, row-major [M][192]
    const bf16* __restrict__ Wpf, const float* __restrict__ bp_,
    const float* __restrict__ Rsrc,                      // x before attn (residual 1)
    const float* __restrict__ lng, const float* __restrict__ lnb,
    const bf16* __restrict__ W1f, const float* __restrict__ b1,
    const bf16* __restrict__ W2f, const float* __restrict__ b2,
    float* __restrict__ Rdst) {
    __shared__ float Xl[64 * XST];       // 50.2 KB x1 tile; first 24.6 KB aliased as Asl
    __shared__ short Bsl[4 * 6 * 512];   // 24.6 KB: LN frags, then hidden-quarter frags
    short* Asl = (short*)Xl;
    int tid = threadIdx.x;
    int bm = blockIdx.x;
    int w = tid >> 6, lane = tid & 63;
    int quad = lane >> 4, l16 = lane & 15;
    // ---- phase 1: stage xnob -> A-frags (R1 gemm_n192 staging, BM=64) ----
    {
        int r = tid >> 2, qq = tid & 3;
        const short* ar = (const short*)Anob + ((size_t)(bm * 64) + r) * 192 + qq * 48;
        #pragma unroll
        for (int j = 0; j < 6; j++) {
            short8 v = *(const short8*)(ar + j * 8);
            int k0 = qq * 48 + j * 8;
            int kt = k0 >> 5, qd = (k0 >> 3) & 3;
            *(short8*)&Asl[((r >> 4) * 6 + kt) * 512 + (qd * 16 + (r & 15)) * 8] = v;
        }
    }
    __syncthreads();
    // ---- phase 2: proj GEMM (R1-proven pattern) ----
    short8 afp[6];
    #pragma unroll
    for (int kt = 0; kt < 6; kt++)
        afp[kt] = *(short8*)&Asl[(w * 6 + kt) * 512 + lane * 8];
    f32x4 acc[12];
    #pragma unroll
    for (int nt = 0; nt < 12; nt++) {
        const short* bp = (const short*)Wpf + ((size_t)nt * 6) * 512 + lane * 8;
        f32x4 a = {};
        #pragma unroll
        for (int kt = 0; kt < 6; kt++) {
            short8 b = *(const short8*)(bp + kt * 512);
            a = __builtin_amdgcn_mfma_f32_16x16x32_bf16(afp[kt], b, a, 0, 0, 0);
        }
        acc[nt] = a;
    }
    __syncthreads();   // all Asl reads done before Xl overwrite
    // ---- phase 3: x1 = acc + bias + residual -> Xl (LDS only, no HBM) ----
    #pragma unroll
    for (int nt = 0; nt < 12; nt++) {
        int col = nt * 16 + l16;
        float bv = bp_[col];
        int lr0 = w * 16 + quad * 4;
        #pragma unroll
        for (int rr = 0; rr < 4; rr++) {
            float rv = Rsrc[(size_t)(bm * 64 + lr0 + rr) * 192 + col];
            Xl[(lr0 + rr) * XST + col] = acc[nt][rr] + bv + rv;
        }
    }
    __syncthreads();
    // ---- phase 4: LN2 from Xl -> LN frags in Bsl (R8 staging, source = LDS) ----
    {
        int r = tid >> 2, qq = tid & 3;
        const float* xr = &Xl[r * XST + qq * 48];
        float4 va[12];
        float s = 0.f, ss = 0.f;
        #pragma unroll
        for (int j = 0; j < 12; j++) {
            va[j] = ((const float4*)xr)[j];
            s  += va[j].x + va[j].y + va[j].z + va[j].w;
            ss += va[j].x * va[j].x + va[j].y * va[j].y + va[j].z * va[j].z + va[j].w * va[j].w;
        }
        s  += __shfl_xor(s, 1);  s  += __shfl_xor(s, 2);
        ss += __shfl_xor(ss, 1); ss += __shfl_xor(ss, 2);
        float mean = s * (1.f / 192.f);
        float var  = ss * (1.f / 192.f) - mean * mean;
        float rs   = rsqrtf(var + 1e-5f);
        const float4* gg = (const float4*)(lng + qq * 48);
        const float4* bb = (const float4*)(lnb + qq * 48);
        #pragma unroll
        for (int j = 0; j < 6; j++) {
            float4 g0 = gg[2 * j], g1 = gg[2 * j + 1], b0 = bb[2 * j], b1v = bb[2 * j + 1];
            float4 x0 = va[2 * j], x1 = va[2 * j + 1];
            short8 o;
            o[0] = f2bbits((x0.x - mean) * rs * g0.x + b0.x);
            o[1] = f2bbits((x0.y - mean) * rs * g0.y + b0.y);
            o[2] = f2bbits((x0.z - mean) * rs * g0.z + b0.z);
            o[3] = f2bbits((x0.w - mean) * rs * g0.w + b0.w);
            o[4] = f2bbits((x1.x - mean) * rs * g1.x + b1v.x);
            o[5] = f2bbits((x1.y - mean) * rs * g1.y + b1v.y);
            o[6] = f2bbits((x1.z - mean) * rs * g1.z + b1v.z);
            o[7] = f2bbits((x1.w - mean) * rs * g1.w + b1v.w);
            int k0 = qq * 48 + j * 8;
            int kt = k0 >> 5, qd = (k0 >> 3) & 3;
            *(short8*)&Bsl[((r >> 4) * 6 + kt) * 512 + (qd * 16 + (r & 15)) * 8] = o;
        }
    }
    __syncthreads();
    // hoist LN A-frags to regs (frees Bsl to become the hidden buffer)
    short8 af[4][6];
    #pragma unroll
    for (int mt = 0; mt < 4; mt++)
        #pragma unroll
        for (int kt = 0; kt < 6; kt++)
            af[mt][kt] = *(short8*)&Bsl[(mt * 6 + kt) * 512 + lane * 8];
    // ---- phase 5: MLP quarters (R8 mlp_fused, verbatim logic) ----
    f32x4 acc2[3][4] = {};
    for (int qtr = 0; qtr < 4; qtr++) {
        __syncthreads();   // af reads (qtr=0) / prior fc2 reads (qtr>0) done
        #pragma unroll
        for (int j = 0; j < 3; j++) {
            int nth = w * 3 + j;
            int ntg = qtr * 12 + nth;
            const short* bp = (const short*)W1f + ((size_t)ntg * 6) * 512 + lane * 8;
            short8 bfr[6];
            #pragma unroll
            for (int kt = 0; kt < 6; kt++) bfr[kt] = *(const short8*)(bp + kt * 512);
            #pragma unroll
            for (int mt = 0; mt < 4; mt++) {
                f32x4 a = {};
                #pragma unroll
                for (int kt = 0; kt < 6; kt++)
                    a = __builtin_amdgcn_mfma_f32_16x16x32_bf16(bfr[kt], af[mt][kt], a, 0, 0, 0);  // C^T
                int colb = ntg * 16 + quad * 4;
                s16x4 o;
                #pragma unroll
                for (int rr = 0; rr < 4; rr++) {
                    float u = a[rr] + b1[colb + rr];
                    float inner = 0.7978845608028654f * (u + 0.044715f * u * u * u);
                    inner = fminf(fmaxf(inner, -12.f), 12.f);
                    float e = __expf(2.f * inner);
                    o[rr] = f2bbits(0.5f * u * (1.f + (e - 1.f) / (e + 1.f)));
                }
                *(s16x4*)&Bsl[(mt * 6 + (nth >> 1)) * 512
                              + (((nth & 1) * 2 + (quad >> 1)) * 16 + l16) * 8 + (quad & 1) * 4] = o;
            }
        }
        __syncthreads();
        #pragma unroll
        for (int kt = 0; kt < 6; kt++) {
            short8 afh[4];
            #pragma unroll
            for (int mt = 0; mt < 4; mt++)
                afh[mt] = *(short8*)&Bsl[(mt * 6 + kt) * 512 + lane * 8];
            #pragma unroll
            for (int j = 0; j < 3; j++) {
                int nt = w * 3 + j;
                const short* bp = (const short*)W2f + ((size_t)nt * 24 + qtr * 6 + kt) * 512 + lane * 8;
                short8 b = *(const short8*)bp;
                #pragma unroll
                for (int mt = 0; mt < 4; mt++)
                    acc2[j][mt] = __builtin_amdgcn_mfma_f32_16x16x32_bf16(afh[mt], b, acc2[j][mt], 0, 0, 0);
            }
        }
    }
    // ---- phase 6: epilogue — bias + residual (from Xl) -> global ----
    #pragma unroll
    for (int j = 0; j < 3; j++) {
        int col = (w * 3 + j) * 16 + l16;
        float bv = b2[col];
        #pragma unroll
        for (int mt = 0; mt < 4; mt++) {
            int lr0 = mt * 16 + quad * 4;
            #pragma unroll
            for (int rr = 0; rr < 4; rr++) {
                size_t idx = (size_t)(bm * 64 + lr0 + rr) * 192 + col;
                Rdst[idx] = acc2[j][mt][rr] + bv + Xl[(lr0 + rr) * XST + col];
            }
        }
    }
}

// ---- MFMA cluster attention: one wave per (head, cluster, batch) ----
#define PST 72   // P LDS row stride (shorts), 16B-aligned rows
#define VST 72   // vT LDS row stride
#define OST 40   // O  LDS row stride
__global__ __launch_bounds__(64) void attn_mfma(const bf16* __restrict__ qkv,
                                                const int* __restrict__ order,
                                                bf16* __restrict__ outb) {
    __shared__ short vT[32 * VST];   // [d][p]
    __shared__ short Pl[64 * PST];   // [qrow][p]; reused as O [qrow][d] stride OST
    const float scale = 0.17677669529663687f;  // 32^-0.5
    int h = blockIdx.x, c = blockIdx.y, b = blockIdx.z;
    int lane = threadIdx.x;
    int l16 = lane & 15, quad = lane >> 4;
    int t = (int)(((unsigned)order[(size_t)b * N_ + c * MCL + lane]) & (N_ - 1));
    const short* qb = (const short*)qkv + (size_t)b * N_ * 576;
    {
        const short* vp = qb + (size_t)t * 576 + 384 + h * 32;
        short8 v[4];
        #pragma unroll
        for (int i = 0; i < 4; i++) v[i] = *(const short8*)(vp + i * 8);
        #pragma unroll
        for (int i = 0; i < 4; i++)
            #pragma unroll
            for (int e = 0; e < 8; e++)
                vT[(i * 8 + e) * VST + lane] = v[i][e];
    }
    short8 aq[4], bk[4];
    #pragma unroll
    for (int i = 0; i < 4; i++) {
        int tr = __shfl(t, i * 16 + l16);
        const short* rp = qb + (size_t)tr * 576 + h * 32 + quad * 8;
        aq[i] = *(const short8*)rp;
        bk[i] = *(const short8*)(rp + 192);
    }
    f32x4 S[4][4];
    #pragma unroll
    for (int mt = 0; mt < 4; mt++)
        #pragma unroll
        for (int nt = 0; nt < 4; nt++) {
            f32x4 z = {};
            S[mt][nt] = __builtin_amdgcn_mfma_f32_16x16x32_bf16(aq[mt], bk[nt], z, 0, 0, 0);
        }
    __syncthreads();
    #pragma unroll
    for (int mt = 0; mt < 4; mt++)
        #pragma unroll
        for (int r = 0; r < 4; r++) {
            float e0, e1, e2, e3, s;
            float v0 = S[mt][0][r] * scale, v1 = S[mt][1][r] * scale;
            float v2 = S[mt][2][r] * scale, v3 = S[mt][3][r] * scale;
            e0 = __expf(fminf(fmaxf(v0, -30.f), 30.f));
            e1 = __expf(fminf(fmaxf(v1, -30.f), 30.f));
            e2 = __expf(fminf(fmaxf(v2, -30.f), 30.f));
            e3 = __expf(fminf(fmaxf(v3, -30.f), 30.f));
            s = e0 + e1 + e2 + e3;
            s += __shfl_xor(s, 1); s += __shfl_xor(s, 2);
            s += __shfl_xor(s, 4); s += __shfl_xor(s, 8);
            float inv = 1.f / s;
            int row = mt * 16 + quad * 4 + r;
            Pl[row * PST +  0 + l16] = f2bbits(e0 * inv);
            Pl[row * PST + 16 + l16] = f2bbits(e1 * inv);
            Pl[row * PST + 32 + l16] = f2bbits(e2 * inv);
            Pl[row * PST + 48 + l16] = f2bbits(e3 * inv);
        }
    __syncthreads();
    short8 ap[4][2], bv[2][2];
    #pragma unroll
    for (int mt = 0; mt < 4; mt++)
        #pragma unroll
        for (int kt = 0; kt < 2; kt++)
            ap[mt][kt] = *(const short8*)&Pl[(mt * 16 + l16) * PST + kt * 32 + quad * 8];
    #pragma unroll
    for (int nt = 0; nt < 2; nt++)
        #pragma unroll
        for (int kt = 0; kt < 2; kt++)
            bv[nt][kt] = *(const short8*)&vT[(nt * 16 + l16) * VST + kt * 32 + quad * 8];
    f32x4 O[4][2] = {};
    #pragma unroll
    for (int mt = 0; mt < 4; mt++)
        #pragma unroll
        for (int nt = 0; nt < 2; nt++)
            #pragma unroll
            for (int kt = 0; kt < 2; kt++)
                O[mt][nt] = __builtin_amdgcn_mfma_f32_16x16x32_bf16(ap[mt][kt], bv[nt][kt], O[mt][nt], 0, 0, 0);
    __syncthreads();
    short* Ol = Pl;
    #pragma unroll
    for (int mt = 0; mt < 4; mt++) {
        int row = mt * 16 + quad * 4;
        #pragma unroll
        for (int nt = 0; nt < 2; nt++)
            #pragma unroll
            for (int rr = 0; rr < 4; rr++)
                Ol[(row + rr) * OST + nt * 16 + l16] = f2bbits(O[mt][nt][rr]);
    }
    __syncthreads();
    short* op = (short*)outb + ((size_t)b * N_ + t) * 192 + h * 32;
    #pragma unroll
    for (int j = 0; j < 4; j++)
        *(short8*)(op + j * 8) = *(const short8*)&Ol[lane * OST + j * 8];
}

extern "C" void kernel_launch(void* const* d_in, const int* in_sizes, int n_in,
                              void* d_out, int out_size, void* d_ws, size_t ws_size,
                              hipStream_t stream) {
    const float* x_in   = (const float*)d_in[0];
    const float* pos    = (const float*)d_in[1];
    const float* ln1_g  = (const float*)d_in[2];
    const float* ln1_b  = (const float*)d_in[3];
    const float* w_qkv  = (const float*)d_in[4];
    const float* b_qkv  = (const float*)d_in[5];
    const float* w_proj = (const float*)d_in[6];
    const float* b_proj = (const float*)d_in[7];
    const float* ln2_g  = (const float*)d_in[8];
    const float* ln2_b  = (const float*)d_in[9];
    const float* w_fc1  = (const float*)d_in[10];
    const float* b_fc1  = (const float*)d_in[11];
    const float* w_fc2  = (const float*)d_in[12];
    const float* b_fc2  = (const float*)d_in[13];

    size_t sz_x     = (size_t)MTOK * D_ * 4;        // 50.3 MB fp32 residual
    size_t sz_xnob  = (size_t)MTOK * D_ * 2;        // 25.2 MB attn out bf16
    size_t sz_cbuf  = (size_t)MTOK * DFF * 2;       // 100.7 MB qkv buffer
    size_t sz_order = (size_t)B_ * N_ * 4;          //  0.26 MB
    size_t sz_wbuf  = (size_t)2 * 442368 * 2;       //  1.73 MB frag-order weights
    size_t need = sz_x + sz_xnob + sz_cbuf + sz_order + sz_wbuf;
    if (ws_size < need) {
        zero_out_kernel<<<(out_size + 255) / 256, 256, 0, stream>>>((float*)d_out, (size_t)out_size);
        return;
    }
    char* ws = (char*)d_ws;
    float* x_f32 = (float*)ws;  ws += sz_x;
    bf16*  xnob  = (bf16*)ws;   ws += sz_xnob;
    bf16*  cbuf  = (bf16*)ws;   ws += sz_cbuf;
    int*   order = (int*)ws;    ws += sz_order;
    bf16*  wbuf  = (bf16*)ws;   ws += sz_wbuf;

    bf16* wq[2]; bf16* wp[2]; bf16* wf1[2]; bf16* wf2[2];
    for (int l = 0; l < 2; ++l) {
        bf16* p = wbuf + (size_t)l * 442368;
        wq[l]  = p;
        wp[l]  = p + 110592;
        wf1[l] = p + 147456;
        wf2[l] = p + 294912;
    }
    wprep_all<<<(2 * 442368 + 255) / 256, 256, 0, stream>>>(w_qkv, w_proj, w_fc1, w_fc2, wbuf);
    build_idx<<<(B_ * N_ + 255) / 256, 256, 0, stream>>>(pos, order);

    for (int l = 0; l < 2; ++l) {
        const float* xsrc = (l == 0) ? x_in : x_f32;
        float* rdst = (l == 1) ? (float*)d_out : x_f32;
        gemm_lnk192<false><<<MTOK / 64, 256, 0, stream>>>(
            xsrc, ln1_g + l * D_, ln1_b + l * D_, wq[l], b_qkv + l * 576, cbuf, 576);
        attn_mfma<<<dim3(H6, KC, B_), 64, 0, stream>>>(cbuf, order, xnob);
        pm_fused<<<MTOK / 64, 256, 0, stream>>>(
            xnob, wp[l], b_proj + l * 192, xsrc,
            ln2_g + l * D_, ln2_b + l * D_,
            wf1[l], b_fc1 + l * 768, wf2[l], b_fc2 + l * 192,
            rdst);
    }
}

// Round 10
// 440.256 us; speedup vs baseline: 1.9440x; 1.1596x over previous
//
#include <hip/hip_runtime.h>
#include <hip/hip_bf16.h>

typedef __hip_bfloat16 bf16;
typedef __attribute__((ext_vector_type(8))) short short8;
typedef __attribute__((ext_vector_type(4))) short s16x4;
typedef __attribute__((ext_vector_type(4))) float f32x4;

#define B_   4
#define N_   16384
#define D_   192
#define H6   6
#define DH   32
#define MCL  64
#define KC   256
#define DFF  768
#define GW   128
#define MTOK (B_ * N_)    // 65536 tokens
#define XST  196          // Xl fp32 row stride in pm_fused
#define PST  72           // P LDS row stride (shorts)
#define OST  40           // O LDS row stride (shorts)

__device__ __forceinline__ bf16 f2b(float x) { return __float2bfloat16(x); }
__device__ __forceinline__ short f2bbits(float x) {
    bf16 h = __float2bfloat16(x); return *(short*)&h;
}

// ---- fallback: zero output (signals ws_size too small via absmax==max|ref|~5.69) ----
__global__ void zero_out_kernel(float* __restrict__ out, size_t n) {
    size_t i = blockIdx.x * (size_t)blockDim.x + threadIdx.x;
    if (i < n) out[i] = 0.f;
}

// ---- order: scanline keys are a bijection onto 0..n-1 -> direct scatter ----
__global__ void build_idx(const float* __restrict__ pos, int* __restrict__ order) {
    int tid = blockIdx.x * blockDim.x + threadIdx.x;
    if (tid >= B_ * N_) return;
    int b = tid / N_;
    int ix = (int)floorf(pos[(size_t)tid * 2 + 0]);
    int iy = (int)floorf(pos[(size_t)tid * 2 + 1]);
    int key = iy * GW + ((iy & 1) ? (GW - 1 - ix) : ix);
    key = (int)(((unsigned)key) & (N_ - 1));
    order[(size_t)b * N_ + key] = tid % N_;
}

// ---- all-weights prep: fp32 row-major [K][N] -> bf16 MFMA-B-fragment order ----
__global__ void wprep_all(const float* __restrict__ wq, const float* __restrict__ wp,
                          const float* __restrict__ wf1, const float* __restrict__ wf2,
                          bf16* __restrict__ out) {
    int tid = blockIdx.x * blockDim.x + threadIdx.x;
    if (tid >= 2 * 442368) return;
    int l = tid / 442368, r = tid % 442368;
    const float* src; bf16* dst; int K, Nn, e;
    if (r < 110592)      { src = wq  + (size_t)l * 110592; dst = out + (size_t)l * 442368;          K = 192; Nn = 576; e = r; }
    else if (r < 147456) { src = wp  + (size_t)l * 36864;  dst = out + (size_t)l * 442368 + 110592; K = 192; Nn = 192; e = r - 110592; }
    else if (r < 294912) { src = wf1 + (size_t)l * 147456; dst = out + (size_t)l * 442368 + 147456; K = 192; Nn = 768; e = r - 147456; }
    else                 { src = wf2 + (size_t)l * 147456; dst = out + (size_t)l * 442368 + 294912; K = 768; Nn = 192; e = r - 294912; }
    int k = e / Nn, n = e % Nn;
    int idx = ((n >> 4) * (K >> 5) + (k >> 5)) * 512 + (((k >> 3) & 3) * 16 + (n & 15)) * 8 + (k & 7);
    dst[idx] = f2b(src[e]);
}

// ---- Kernel QA: fused gather + LN1 + qkv GEMM + cluster attention ----
// Block = (cluster, batch), 384 threads = 6 waves = 6 heads.
// qkv (75MB/layer) never touches HBM: Q/K/V staged in LDS as MFMA fragments.
// Q,K via swapped-mfma C^T -> s16x4 frag store (R5-verified formula);
// V via normal-mfma C -> mirrored frag store. One barrier total.
__global__ __launch_bounds__(384) void qa_fused(
    const float* __restrict__ xsrc, const int* __restrict__ order,
    const float* __restrict__ lng, const float* __restrict__ lnb,
    const bf16* __restrict__ Wqf, const float* __restrict__ bq,
    bf16* __restrict__ outb) {
    __shared__ short Asl[4 * 6 * 512];      // 24.6 KB LN(x) A-frags [mt][kt]
    __shared__ short Qf[4 * 6 * 512];       // 24.6 KB Q A-frags [mt][head]
    __shared__ short Kf[4 * 6 * 512];       // 24.6 KB K B-frags [nt_tok][head]
    __shared__ short Vf[6 * 4 * 512];       // 24.6 KB V B-frags [head][ntv*2+ktv]
    __shared__ short Pm[6 * 64 * PST];      // 55.3 KB per-head P (O staging aliases)
    const float scale = 0.17677669529663687f;  // 32^-0.5
    int c = blockIdx.x, b = blockIdx.y;
    int tid = threadIdx.x;
    int w = tid >> 6, lane = tid & 63;
    int quad = lane >> 4, l16 = lane & 15;
    int t = (int)(((unsigned)order[(size_t)b * N_ + c * MCL + lane]) & (N_ - 1));
    // ---- phase 1: gather x rows + LN -> Asl (256 threads, 4/row; waves 4-5 idle) ----
    if (tid < 256) {
        int r = tid >> 2, qq = tid & 3;
        int tr = (int)(((unsigned)order[(size_t)b * N_ + c * MCL + r]) & (N_ - 1));
        const float* xr = xsrc + ((size_t)b * N_ + tr) * 192 + qq * 48;
        float4 va[12];
        float s = 0.f, ss = 0.f;
        #pragma unroll
        for (int j = 0; j < 12; j++) {
            va[j] = ((const float4*)xr)[j];
            s  += va[j].x + va[j].y + va[j].z + va[j].w;
            ss += va[j].x * va[j].x + va[j].y * va[j].y + va[j].z * va[j].z + va[j].w * va[j].w;
        }
        s  += __shfl_xor(s, 1);  s  += __shfl_xor(s, 2);
        ss += __shfl_xor(ss, 1); ss += __shfl_xor(ss, 2);
        float mean = s * (1.f / 192.f);
        float var  = ss * (1.f / 192.f) - mean * mean;
        float rs   = rsqrtf(var + 1e-5f);
        const float4* gg = (const float4*)(lng + qq * 48);
        const float4* bb = (const float4*)(lnb + qq * 48);
        #pragma unroll
        for (int j = 0; j < 6; j++) {
            float4 g0 = gg[2 * j], g1 = gg[2 * j + 1], b0 = bb[2 * j], b1v = bb[2 * j + 1];
            float4 x0 = va[2 * j], x1 = va[2 * j + 1];
            short8 o;
            o[0] = f2bbits((x0.x - mean) * rs * g0.x + b0.x);
            o[1] = f2bbits((x0.y - mean) * rs * g0.y + b0.y);
            o[2] = f2bbits((x0.z - mean) * rs * g0.z + b0.z);
            o[3] = f2bbits((x0.w - mean) * rs * g0.w + b0.w);
            o[4] = f2bbits((x1.x - mean) * rs * g1.x + b1v.x);
            o[5] = f2bbits((x1.y - mean) * rs * g1.y + b1v.y);
            o[6] = f2bbits((x1.z - mean) * rs * g1.z + b1v.z);
            o[7] = f2bbits((x1.w - mean) * rs * g1.w + b1v.w);
            int k0 = qq * 48 + j * 8;
            int kt = k0 >> 5, qd = (k0 >> 3) & 3;
            *(short8*)&Asl[((r >> 4) * 6 + kt) * 512 + (qd * 16 + (r & 15)) * 8] = o;
        }
    }
    __syncthreads();   // the only block-wide barrier
    // ---- phase 2: qkv GEMM for own head (wave w = head w) ----
    short8 af[4][6];
    #pragma unroll
    for (int mt = 0; mt < 4; mt++)
        #pragma unroll
        for (int kt = 0; kt < 6; kt++)
            af[mt][kt] = *(short8*)&Asl[(mt * 6 + kt) * 512 + lane * 8];
    // Q (s=0,1) and K (s=2,3): swapped mfma -> C^T -> frag store
    #pragma unroll
    for (int s = 0; s < 4; s++) {
        int isK = s >> 1, q = s & 1;
        int nt = isK * 12 + 2 * w + q;
        const short* bp = (const short*)Wqf + ((size_t)nt * 6) * 512 + lane * 8;
        short8 bfr[6];
        #pragma unroll
        for (int kt = 0; kt < 6; kt++) bfr[kt] = *(const short8*)(bp + kt * 512);
        float4 bvq = *(const float4*)(bq + nt * 16 + quad * 4);
        short* dstb = isK ? Kf : Qf;
        #pragma unroll
        for (int mt = 0; mt < 4; mt++) {
            f32x4 a = {};
            #pragma unroll
            for (int kt = 0; kt < 6; kt++)
                a = __builtin_amdgcn_mfma_f32_16x16x32_bf16(bfr[kt], af[mt][kt], a, 0, 0, 0);  // C^T
            s16x4 o;
            o[0] = f2bbits(a[0] + bvq.x); o[1] = f2bbits(a[1] + bvq.y);
            o[2] = f2bbits(a[2] + bvq.z); o[3] = f2bbits(a[3] + bvq.w);
            *(s16x4*)&dstb[(mt * 6 + w) * 512
                           + ((q * 2 + (quad >> 1)) * 16 + l16) * 8 + (quad & 1) * 4] = o;
        }
    }
    // V: normal mfma -> C layout -> B-frag store (n=dim, k=token)
    #pragma unroll
    for (int q = 0; q < 2; q++) {
        int nt = 24 + 2 * w + q;
        const short* bp = (const short*)Wqf + ((size_t)nt * 6) * 512 + lane * 8;
        short8 bfr[6];
        #pragma unroll
        for (int kt = 0; kt < 6; kt++) bfr[kt] = *(const short8*)(bp + kt * 512);
        float bvv = bq[nt * 16 + l16];
        #pragma unroll
        for (int mt = 0; mt < 4; mt++) {
            f32x4 a = {};
            #pragma unroll
            for (int kt = 0; kt < 6; kt++)
                a = __builtin_amdgcn_mfma_f32_16x16x32_bf16(af[mt][kt], bfr[kt], a, 0, 0, 0);
            s16x4 o;
            #pragma unroll
            for (int rr = 0; rr < 4; rr++) o[rr] = f2bbits(a[rr] + bvv);
            *(s16x4*)&Vf[((w * 2 + q) * 2 + (mt >> 1)) * 512
                         + (((mt & 1) * 2 + (quad >> 1)) * 16 + l16) * 8 + (quad & 1) * 4] = o;
        }
    }
    // ---- phase 3: attention (verbatim structure; frags from LDS, all same-wave) ----
    short8 aq[4], bk[4];
    #pragma unroll
    for (int i = 0; i < 4; i++) {
        aq[i] = *(short8*)&Qf[(i * 6 + w) * 512 + lane * 8];
        bk[i] = *(short8*)&Kf[(i * 6 + w) * 512 + lane * 8];
    }
    f32x4 S[4][4];
    #pragma unroll
    for (int mt = 0; mt < 4; mt++)
        #pragma unroll
        for (int nt = 0; nt < 4; nt++) {
            f32x4 z = {};
            S[mt][nt] = __builtin_amdgcn_mfma_f32_16x16x32_bf16(aq[mt], bk[nt], z, 0, 0, 0);
        }
    short* Pl = Pm + w * 64 * PST;
    #pragma unroll
    for (int mt = 0; mt < 4; mt++)
        #pragma unroll
        for (int r = 0; r < 4; r++) {
            float e0, e1, e2, e3, s;
            float v0 = S[mt][0][r] * scale, v1 = S[mt][1][r] * scale;
            float v2 = S[mt][2][r] * scale, v3 = S[mt][3][r] * scale;
            e0 = __expf(fminf(fmaxf(v0, -30.f), 30.f));
            e1 = __expf(fminf(fmaxf(v1, -30.f), 30.f));
            e2 = __expf(fminf(fmaxf(v2, -30.f), 30.f));
            e3 = __expf(fminf(fmaxf(v3, -30.f), 30.f));
            s = e0 + e1 + e2 + e3;
            s += __shfl_xor(s, 1); s += __shfl_xor(s, 2);
            s += __shfl_xor(s, 4); s += __shfl_xor(s, 8);
            float inv = 1.f / s;
            int row = mt * 16 + quad * 4 + r;
            Pl[row * PST +  0 + l16] = f2bbits(e0 * inv);
            Pl[row * PST + 16 + l16] = f2bbits(e1 * inv);
            Pl[row * PST + 32 + l16] = f2bbits(e2 * inv);
            Pl[row * PST + 48 + l16] = f2bbits(e3 * inv);
        }
    short8 ap[4][2], bv[2][2];
    #pragma unroll
    for (int mt = 0; mt < 4; mt++)
        #pragma unroll
        for (int kt = 0; kt < 2; kt++)
            ap[mt][kt] = *(const short8*)&Pl[(mt * 16 + l16) * PST + kt * 32 + quad * 8];
    #pragma unroll
    for (int nt = 0; nt < 2; nt++)
        #pragma unroll
        for (int kt = 0; kt < 2; kt++)
            bv[nt][kt] = *(const short8*)&Vf[((w * 2 + nt) * 2 + kt) * 512 + lane * 8];
    f32x4 O[4][2] = {};
    #pragma unroll
    for (int mt = 0; mt < 4; mt++)
        #pragma unroll
        for (int nt = 0; nt < 2; nt++)
            #pragma unroll
            for (int kt = 0; kt < 2; kt++)
                O[mt][nt] = __builtin_amdgcn_mfma_f32_16x16x32_bf16(ap[mt][kt], bv[nt][kt], O[mt][nt], 0, 0, 0);
    short* Ol = Pl;   // same-wave alias; LDS ops ordered within wave
    #pragma unroll
    for (int mt = 0; mt < 4; mt++) {
        int row = mt * 16 + quad * 4;
        #pragma unroll
        for (int nt = 0; nt < 2; nt++)
            #pragma unroll
            for (int rr = 0; rr < 4; rr++)
                Ol[(row + rr) * OST + nt * 16 + l16] = f2bbits(O[mt][nt][rr]);
    }
    short* op = (short*)outb + ((size_t)b * N_ + t) * 192 + w * 32;
    #pragma unroll
    for (int j = 0; j < 4; j++)
        *(short8*)(op + j * 8) = *(const short8*)&Ol[lane * OST + j * 8];
}

// ---- Kernel C: fused proj + residual + LN2 + MLP + residual, BM=64 (R9, measured 122us) ----
__global__ __launch_bounds__(256) void pm_fused(
    const bf16* __restrict__ Anob,
    const bf16* __restrict__ Wpf, const float* __restrict__ bp_,
    const float* __restrict__ Rsrc,
    const float* __restrict__ lng, const float* __restrict__ lnb,
    const bf16* __restrict__ W1f, const float* __restrict__ b1,
    const bf16* __restrict__ W2f, const float* __restrict__ b2,
    float* __restrict__ Rdst) {
    __shared__ float Xl[64 * XST];
    __shared__ short Bsl[4 * 6 * 512];
    short* Asl = (short*)Xl;
    int tid = threadIdx.x;
    int bm = blockIdx.x;
    int w = tid >> 6, lane = tid & 63;
    int quad = lane >> 4, l16 = lane & 15;
    {
        int r = tid >> 2, qq = tid & 3;
        const short* ar = (const short*)Anob + ((size_t)(bm * 64) + r) * 192 + qq * 48;
        #pragma unroll
        for (int j = 0; j < 6; j++) {
            short8 v = *(const short8*)(ar + j * 8);
            int k0 = qq * 48 + j * 8;
            int kt = k0 >> 5, qd = (k0 >> 3) & 3;
            *(short8*)&Asl[((r >> 4) * 6 + kt) * 512 + (qd * 16 + (r & 15)) * 8] = v;
        }
    }
    __syncthreads();
    short8 afp[6];
    #pragma unroll
    for (int kt = 0; kt < 6; kt++)
        afp[kt] = *(short8*)&Asl[(w * 6 + kt) * 512 + lane * 8];
    f32x4 acc[12];
    #pragma unroll
    for (int nt = 0; nt < 12; nt++) {
        const short* bp = (const short*)Wpf + ((size_t)nt * 6) * 512 + lane * 8;
        f32x4 a = {};
        #pragma unroll
        for (int kt = 0; kt < 6; kt++) {
            short8 b = *(const short8*)(bp + kt * 512);
            a = __builtin_amdgcn_mfma_f32_16x16x32_bf16(afp[kt], b, a, 0, 0, 0);
        }
        acc[nt] = a;
    }
    __syncthreads();
    #pragma unroll
    for (int nt = 0; nt < 12; nt++) {
        int col = nt * 16 + l16;
        float bv = bp_[col];
        int lr0 = w * 16 + quad * 4;
        #pragma unroll
        for (int rr = 0; rr < 4; rr++) {
            float rv = Rsrc[(size_t)(bm * 64 + lr0 + rr) * 192 + col];
            Xl[(lr0 + rr) * XST + col] = acc[nt][rr] + bv + rv;
        }
    }
    __syncthreads();
    {
        int r = tid >> 2, qq = tid & 3;
        const float* xr = &Xl[r * XST + qq * 48];
        float4 va[12];
        float s = 0.f, ss = 0.f;
        #pragma unroll
        for (int j = 0; j < 12; j++) {
            va[j] = ((const float4*)xr)[j];
            s  += va[j].x + va[j].y + va[j].z + va[j].w;
            ss += va[j].x * va[j].x + va[j].y * va[j].y + va[j].z * va[j].z + va[j].w * va[j].w;
        }
        s  += __shfl_xor(s, 1);  s  += __shfl_xor(s, 2);
        ss += __shfl_xor(ss, 1); ss += __shfl_xor(ss, 2);
        float mean = s * (1.f / 192.f);
        float var  = ss * (1.f / 192.f) - mean * mean;
        float rs   = rsqrtf(var + 1e-5f);
        const float4* gg = (const float4*)(lng + qq * 48);
        const float4* bb = (const float4*)(lnb + qq * 48);
        #pragma unroll
        for (int j = 0; j < 6; j++) {
            float4 g0 = gg[2 * j], g1 = gg[2 * j + 1], b0 = bb[2 * j], b1v = bb[2 * j + 1];
            float4 x0 = va[2 * j], x1 = va[2 * j + 1];
            short8 o;
            o[0] = f2bbits((x0.x - mean) * rs * g0.x + b0.x);
            o[1] = f2bbits((x0.y - mean) * rs * g0.y + b0.y);
            o[2] = f2bbits((x0.z - mean) * rs * g0.z + b0.z);
            o[3] = f2bbits((x0.w - mean) * rs * g0.w + b0.w);
            o[4] = f2bbits((x1.x - mean) * rs * g1.x + b1v.x);
            o[5] = f2bbits((x1.y - mean) * rs * g1.y + b1v.y);
            o[6] = f2bbits((x1.z - mean) * rs * g1.z + b1v.z);
            o[7] = f2bbits((x1.w - mean) * rs * g1.w + b1v.w);
            int k0 = qq * 48 + j * 8;
            int kt = k0 >> 5, qd = (k0 >> 3) & 3;
            *(short8*)&Bsl[((r >> 4) * 6 + kt) * 512 + (qd * 16 + (r & 15)) * 8] = o;
        }
    }
    __syncthreads();
    short8 af[4][6];
    #pragma unroll
    for (int mt = 0; mt < 4; mt++)
        #pragma unroll
        for (int kt = 0; kt < 6; kt++)
            af[mt][kt] = *(short8*)&Bsl[(mt * 6 + kt) * 512 + lane * 8];
    f32x4 acc2[3][4] = {};
    for (int qtr = 0; qtr < 4; qtr++) {
        __syncthreads();
        #pragma unroll
        for (int j = 0; j < 3; j++) {
            int nth = w * 3 + j;
            int ntg = qtr * 12 + nth;
            const short* bp = (const short*)W1f + ((size_t)ntg * 6) * 512 + lane * 8;
            short8 bfr[6];
            #pragma unroll
            for (int kt = 0; kt < 6; kt++) bfr[kt] = *(const short8*)(bp + kt * 512);
            #pragma unroll
            for (int mt = 0; mt < 4; mt++) {
                f32x4 a = {};
                #pragma unroll
                for (int kt = 0; kt < 6; kt++)
                    a = __builtin_amdgcn_mfma_f32_16x16x32_bf16(bfr[kt], af[mt][kt], a, 0, 0, 0);  // C^T
                int colb = ntg * 16 + quad * 4;
                s16x4 o;
                #pragma unroll
                for (int rr = 0; rr < 4; rr++) {
                    float u = a[rr] + b1[colb + rr];
                    float inner = 0.7978845608028654f * (u + 0.044715f * u * u * u);
                    inner = fminf(fmaxf(inner, -12.f), 12.f);
                    float e = __expf(2.f * inner);
                    o[rr] = f2bbits(0.5f * u * (1.f + (e - 1.f) / (e + 1.f)));
                }
                *(s16x4*)&Bsl[(mt * 6 + (nth >> 1)) * 512
                              + (((nth & 1) * 2 + (quad >> 1)) * 16 + l16) * 8 + (quad & 1) * 4] = o;
            }
        }
        __syncthreads();
        #pragma unroll
        for (int kt = 0; kt < 6; kt++) {
            short8 afh[4];
            #pragma unroll
            for (int mt = 0; mt < 4; mt++)
                afh[mt] = *(short8*)&Bsl[(mt * 6 + kt) * 512 + lane * 8];
            #pragma unroll
            for (int j = 0; j < 3; j++) {
                int nt = w * 3 + j;
                const short* bp = (const short*)W2f + ((size_t)nt * 24 + qtr * 6 + kt) * 512 + lane * 8;
                short8 b = *(const short8*)bp;
                #pragma unroll
                for (int mt = 0; mt < 4; mt++)
                    acc2[j][mt] = __builtin_amdgcn_mfma_f32_16x16x32_bf16(afh[mt], b, acc2[j][mt], 0, 0, 0);
            }
        }
    }
    #pragma unroll
    for (int j = 0; j < 3; j++) {
        int col = (w * 3 + j) * 16 + l16;
        float bv = b2[col];
        #pragma unroll
        for (int mt = 0; mt < 4; mt++) {
            int lr0 = mt * 16 + quad * 4;
            #pragma unroll
            for (int rr = 0; rr < 4; rr++) {
                size_t idx = (size_t)(bm * 64 + lr0 + rr) * 192 + col;
                Rdst[idx] = acc2[j][mt][rr] + bv + Xl[(lr0 + rr) * XST + col];
            }
        }
    }
}

extern "C" void kernel_launch(void* const* d_in, const int* in_sizes, int n_in,
                              void* d_out, int out_size, void* d_ws, size_t ws_size,
                              hipStream_t stream) {
    const float* x_in   = (const float*)d_in[0];
    const float* pos    = (const float*)d_in[1];
    const float* ln1_g  = (const float*)d_in[2];
    const float* ln1_b  = (const float*)d_in[3];
    const float* w_qkv  = (const float*)d_in[4];
    const float* b_qkv  = (const float*)d_in[5];
    const float* w_proj = (const float*)d_in[6];
    const float* b_proj = (const float*)d_in[7];
    const float* ln2_g  = (const float*)d_in[8];
    const float* ln2_b  = (const float*)d_in[9];
    const float* w_fc1  = (const float*)d_in[10];
    const float* b_fc1  = (const float*)d_in[11];
    const float* w_fc2  = (const float*)d_in[12];
    const float* b_fc2  = (const float*)d_in[13];

    size_t sz_x     = (size_t)MTOK * D_ * 4;        // 50.3 MB fp32 residual
    size_t sz_xnob  = (size_t)MTOK * D_ * 2;        // 25.2 MB attn out bf16
    size_t sz_order = (size_t)B_ * N_ * 4;          //  0.26 MB
    size_t sz_wbuf  = (size_t)2 * 442368 * 2;       //  1.73 MB frag-order weights
    size_t need = sz_x + sz_xnob + sz_order + sz_wbuf;
    if (ws_size < need) {
        zero_out_kernel<<<(out_size + 255) / 256, 256, 0, stream>>>((float*)d_out, (size_t)out_size);
        return;
    }
    char* ws = (char*)d_ws;
    float* x_f32 = (float*)ws;  ws += sz_x;
    bf16*  xnob  = (bf16*)ws;   ws += sz_xnob;
    int*   order = (int*)ws;    ws += sz_order;
    bf16*  wbuf  = (bf16*)ws;   ws += sz_wbuf;

    bf16* wq[2]; bf16* wp[2]; bf16* wf1[2]; bf16* wf2[2];
    for (int l = 0; l < 2; ++l) {
        bf16* p = wbuf + (size_t)l * 442368;
        wq[l]  = p;
        wp[l]  = p + 110592;
        wf1[l] = p + 147456;
        wf2[l] = p + 294912;
    }
    wprep_all<<<(2 * 442368 + 255) / 256, 256, 0, stream>>>(w_qkv, w_proj, w_fc1, w_fc2, wbuf);
    build_idx<<<(B_ * N_ + 255) / 256, 256, 0, stream>>>(pos, order);

    for (int l = 0; l < 2; ++l) {
        const float* xsrc = (l == 0) ? x_in : x_f32;
        float* rdst = (l == 1) ? (float*)d_out : x_f32;
        qa_fused<<<dim3(KC, B_), 384, 0, stream>>>(
            xsrc, order, ln1_g + l * D_, ln1_b + l * D_,
            wq[l], b_qkv + l * 576, xnob);
        pm_fused<<<MTOK / 64, 256, 0, stream>>>(
            xnob, wp[l], b_proj + l * 192, xsrc,
            ln2_g + l * D_, ln2_b + l * D_,
            wf1[l], b_fc1 + l * 768, wf2[l], b_fc2 + l * 192,
            rdst);
    }
}